// Round 1
// baseline (1030.304 us; speedup 1.0000x reference)
//
#include <hip/hip_runtime.h>
#include <math.h>

#define IN_DIM 128
#define HID_DIM 256
#define OUT_DIM 128
#define HEADS 4
#define N0 80000
#define N1 40000
#define N2 8000
#define E1 400000
#define E2 128000
#define NEG 0.2f

// ---------------- GEMM: C[M,N] = A[M,K] @ B (+bias) ----------------
// BT=false: B is [K,N] row-major.  BT=true: B is [N,K] row-major (C=A.B^T).
template<bool BT, bool BIAS>
__global__ __launch_bounds__(256) void gemm_kernel(
    const float* __restrict__ A, const float* __restrict__ B,
    const float* __restrict__ bias, float* __restrict__ C,
    int M, int N, int K) {
  const int BM = 64, BN = 64, BK = 16;
  __shared__ float As[BK][BM + 1];
  __shared__ float Bs[BK][BN + 1];
  int tid = threadIdx.x;
  int bm = blockIdx.x * BM;
  int bn = blockIdx.y * BN;
  int tx = tid & 15, ty = tid >> 4;
  float acc[4][4] = {};
  for (int k0 = 0; k0 < K; k0 += BK) {
    {
      int k = tid & 15, m = tid >> 4;
#pragma unroll
      for (int i = 0; i < 4; i++) {
        int mm = m + 16 * i;
        int gm = bm + mm;
        float v = 0.f;
        if (gm < M) v = A[(long)gm * K + k0 + k];
        As[k][mm] = v;
      }
    }
    if (!BT) {
      int n = tid & 63, k = tid >> 6;
#pragma unroll
      for (int i = 0; i < 4; i++) {
        int kk = k + 4 * i;
        int gn = bn + n;
        float v = 0.f;
        if (gn < N) v = B[(long)(k0 + kk) * N + gn];
        Bs[kk][n] = v;
      }
    } else {
      int k = tid & 15, n = tid >> 4;
#pragma unroll
      for (int i = 0; i < 4; i++) {
        int nn = n + 16 * i;
        int gn = bn + nn;
        float v = 0.f;
        if (gn < N) v = B[(long)gn * K + k0 + k];
        Bs[k][nn] = v;
      }
    }
    __syncthreads();
#pragma unroll
    for (int k = 0; k < BK; k++) {
      float a[4], b[4];
#pragma unroll
      for (int i = 0; i < 4; i++) a[i] = As[k][ty * 4 + i];
#pragma unroll
      for (int j = 0; j < 4; j++) b[j] = Bs[k][tx * 4 + j];
#pragma unroll
      for (int i = 0; i < 4; i++)
#pragma unroll
        for (int j = 0; j < 4; j++) acc[i][j] += a[i] * b[j];
    }
    __syncthreads();
  }
#pragma unroll
  for (int i = 0; i < 4; i++) {
    int gm = bm + ty * 4 + i;
    if (gm >= M) continue;
#pragma unroll
    for (int j = 0; j < 4; j++) {
      int gn = bn + tx * 4 + j;
      if (gn >= N) continue;
      float v = acc[i][j];
      if (BIAS) v += bias[gn];
      C[(long)gm * N + gn] = v;
    }
  }
}

// ---------------- attn dots, layer 1 ----------------
// per node n: a_s[n,h] = dot(h[n, h*128:(h+1)*128], att_s[h]); same for a_d (n<N1)
__global__ __launch_bounds__(256) void attn1_kernel(
    const float* __restrict__ h, const float* __restrict__ att_s,
    const float* __restrict__ att_d, float* __restrict__ a_s,
    float* __restrict__ a_d) {
  int n = blockIdx.x;
  int tid = threadIdx.x;  // 256; channel c = 2*tid; head = tid>>6 (one wave per head)
  int c = tid * 2;
  float2 hv = *(const float2*)&h[(long)n * 512 + c];
  float2 as = *(const float2*)&att_s[c];
  float2 ad = *(const float2*)&att_d[c];
  float s = hv.x * as.x + hv.y * as.y;
  float d = hv.x * ad.x + hv.y * ad.y;
  for (int off = 32; off >= 1; off >>= 1) {
    s += __shfl_down(s, off);
    d += __shfl_down(d, off);
  }
  if ((tid & 63) == 0) {
    int hd = tid >> 6;
    a_s[n * 4 + hd] = s;
    if (n < N1) a_d[n * 4 + hd] = d;
  }
}

// ---------------- attn dots, layer 2 (heads=1, C=256) ----------------
__global__ __launch_bounds__(256) void attn2_kernel(
    const float* __restrict__ g, const float* __restrict__ att_s,
    const float* __restrict__ att_d, float* __restrict__ a_s,
    float* __restrict__ a_d) {
  __shared__ float red_s[4], red_d[4];
  int n = blockIdx.x;
  int tid = threadIdx.x;
  float hv = g[(long)n * 256 + tid];
  float s = hv * att_s[tid], d = hv * att_d[tid];
  for (int off = 32; off >= 1; off >>= 1) {
    s += __shfl_down(s, off);
    d += __shfl_down(d, off);
  }
  if ((tid & 63) == 0) {
    red_s[tid >> 6] = s;
    red_d[tid >> 6] = d;
  }
  __syncthreads();
  if (tid == 0) {
    a_s[n] = red_s[0] + red_s[1] + red_s[2] + red_s[3];
    if (n < N2) a_d[n] = red_d[0] + red_d[1] + red_d[2] + red_d[3];
  }
}

// ---------------- CSR build ----------------
__global__ void hist_kernel(const int* __restrict__ dst, int E,
                            int* __restrict__ deg) {
  int e = blockIdx.x * blockDim.x + threadIdx.x;
  if (e < E) atomicAdd(&deg[dst[e]], 1);
}

__global__ __launch_bounds__(1024) void scan_kernel(
    const int* __restrict__ deg, int n, int* __restrict__ offs,
    int* __restrict__ cursor) {
  __shared__ int part[1024];
  int tid = threadIdx.x;
  int chunk = (n + 1023) / 1024;
  int lo = tid * chunk, hi = min(n, lo + chunk);
  int s = 0;
  for (int i = lo; i < hi; i++) s += deg[i];
  part[tid] = s;
  __syncthreads();
  for (int off = 1; off < 1024; off <<= 1) {
    int v = (tid >= off) ? part[tid - off] : 0;
    __syncthreads();
    part[tid] += v;
    __syncthreads();
  }
  int base = (tid == 0) ? 0 : part[tid - 1];
  for (int i = lo; i < hi; i++) {
    offs[i] = base;
    cursor[i] = base;
    base += deg[i];
  }
  if (tid == 1023) offs[n] = part[1023];
}

__global__ void scatter_kernel(const int* __restrict__ src,
                               const int* __restrict__ dst, int E,
                               int* __restrict__ cursor,
                               int* __restrict__ csr_src) {
  int e = blockIdx.x * blockDim.x + threadIdx.x;
  if (e < E) {
    int p = atomicAdd(&cursor[dst[e]], 1);
    csr_src[p] = src[e];
  }
}

// ---------------- aggregation layer 1 (heads=4, C=128) ----------------
__global__ __launch_bounds__(256) void agg1_kernel(
    const float* __restrict__ h, const float* __restrict__ a_s,
    const float* __restrict__ a_d, const int* __restrict__ offs,
    const int* __restrict__ csr_src, const float* __restrict__ b1,
    float* __restrict__ out) {
  int d = blockIdx.x, tid = threadIdx.x;
  __shared__ float s_w[64 * 4];
  __shared__ int s_src[64];
  __shared__ float s_red[16];
  __shared__ float s_m[4], s_den[4];
  int lo = offs[d], deg = offs[d + 1] - lo;
  int hd = tid & 3;
  float ad = a_d[d * 4 + hd];
  // phase 1: per-head max
  float mx = -INFINITY;
  for (int e = tid >> 2; e < deg; e += 64) {
    int src = csr_src[lo + e];
    float t = a_s[src * 4 + hd] + ad;
    t = t > 0.f ? t : NEG * t;
    mx = fmaxf(mx, t);
  }
  for (int off = 4; off <= 32; off <<= 1) mx = fmaxf(mx, __shfl_xor(mx, off));
  if ((tid & 63) < 4) s_red[(tid >> 6) * 4 + hd] = mx;
  __syncthreads();
  if (tid < 4)
    s_m[tid] = fmaxf(fmaxf(s_red[tid], s_red[4 + tid]),
                     fmaxf(s_red[8 + tid], s_red[12 + tid]));
  __syncthreads();
  // phase 2: per-head denom
  float m_h = s_m[hd];
  float sm = 0.f;
  for (int e = tid >> 2; e < deg; e += 64) {
    int src = csr_src[lo + e];
    float t = a_s[src * 4 + hd] + ad;
    t = t > 0.f ? t : NEG * t;
    sm += expf(t - m_h);
  }
  for (int off = 4; off <= 32; off <<= 1) sm += __shfl_xor(sm, off);
  if ((tid & 63) < 4) s_red[(tid >> 6) * 4 + hd] = sm;
  __syncthreads();
  if (tid < 4)
    s_den[tid] = s_red[tid] + s_red[4 + tid] + s_red[8 + tid] + s_red[12 + tid] +
                 1e-16f;
  __syncthreads();
  // phase 3: weighted accumulation, chunked by 64 edges
  int ch = tid * 2;
  int hd2 = ch >> 7;  // = wave id
  float accx = 0.f, accy = 0.f;
  for (int c0 = 0; c0 < deg; c0 += 64) {
    int rem = min(64, deg - c0);
    __syncthreads();
    int eloc = tid >> 2;
    if (eloc < rem) {
      int src = csr_src[lo + c0 + eloc];
      if (hd == 0) s_src[eloc] = src;
      float t = a_s[src * 4 + hd] + ad;
      t = t > 0.f ? t : NEG * t;
      s_w[eloc * 4 + hd] = expf(t - s_m[hd]) / s_den[hd];
    }
    __syncthreads();
    for (int j = 0; j < rem; j++) {
      float2 v = *(const float2*)&h[(long)s_src[j] * 512 + ch];
      float w = s_w[j * 4 + hd2];
      accx += w * v.x;
      accy += w * v.y;
    }
  }
  out[(long)d * 512 + ch] = accx + b1[ch];
  out[(long)d * 512 + ch + 1] = accy + b1[ch + 1];
}

// ---------------- aggregation layer 2 (heads=1, C=256) ----------------
__global__ __launch_bounds__(256) void agg2_kernel(
    const float* __restrict__ g, const float* __restrict__ a_s,
    const float* __restrict__ a_d, const int* __restrict__ offs,
    const int* __restrict__ csr_src, const float* __restrict__ b2,
    float* __restrict__ out) {
  int d = blockIdx.x, tid = threadIdx.x;
  __shared__ float s_w[64];
  __shared__ int s_src[64];
  __shared__ float s_red[4];
  int lo = offs[d], deg = offs[d + 1] - lo;
  float ad = a_d[d];
  float mx = -INFINITY;
  for (int e = tid; e < deg; e += 256) {
    float t = a_s[csr_src[lo + e]] + ad;
    t = t > 0.f ? t : NEG * t;
    mx = fmaxf(mx, t);
  }
  for (int off = 32; off >= 1; off >>= 1) mx = fmaxf(mx, __shfl_xor(mx, off));
  if ((tid & 63) == 0) s_red[tid >> 6] = mx;
  __syncthreads();
  mx = fmaxf(fmaxf(s_red[0], s_red[1]), fmaxf(s_red[2], s_red[3]));
  __syncthreads();
  float sm = 0.f;
  for (int e = tid; e < deg; e += 256) {
    float t = a_s[csr_src[lo + e]] + ad;
    t = t > 0.f ? t : NEG * t;
    sm += expf(t - mx);
  }
  for (int off = 32; off >= 1; off >>= 1) sm += __shfl_xor(sm, off);
  if ((tid & 63) == 0) s_red[tid >> 6] = sm;
  __syncthreads();
  float denom = s_red[0] + s_red[1] + s_red[2] + s_red[3] + 1e-16f;
  float acc = 0.f;
  for (int c0 = 0; c0 < deg; c0 += 64) {
    int rem = min(64, deg - c0);
    __syncthreads();
    if (tid < rem) {
      int src = csr_src[lo + c0 + tid];
      s_src[tid] = src;
      float t = a_s[src] + ad;
      t = t > 0.f ? t : NEG * t;
      s_w[tid] = expf(t - mx) / denom;
    }
    __syncthreads();
    for (int j = 0; j < rem; j++) acc += s_w[j] * g[(long)s_src[j] * 256 + tid];
  }
  out[(long)d * 256 + tid] = acc + b2[tid];
}

extern "C" void kernel_launch(void* const* d_in, const int* in_sizes, int n_in,
                              void* d_out, int out_size, void* d_ws,
                              size_t ws_size, hipStream_t stream) {
  const float* x = (const float*)d_in[0];
  const int* es1 = (const int*)d_in[1];
  const int* ed1 = (const int*)d_in[2];
  const int* es2 = (const int*)d_in[3];
  const int* ed2 = (const int*)d_in[4];
  const float* W1 = (const float*)d_in[5];
  const float* att_s1 = (const float*)d_in[6];
  const float* att_d1 = (const float*)d_in[7];
  const float* b1 = (const float*)d_in[8];
  const float* W2 = (const float*)d_in[9];
  const float* att_s2 = (const float*)d_in[10];
  const float* att_d2 = (const float*)d_in[11];
  const float* b2 = (const float*)d_in[12];
  const float* c1w = (const float*)d_in[13];
  const float* c1b = (const float*)d_in[14];
  const float* c2w = (const float*)d_in[15];
  const float* c2b = (const float*)d_in[16];
  float* out = (float*)d_out;

  char* ws = (char*)d_ws;
  size_t off = 0;
  auto alloc = [&](size_t bytes) {
    void* p = ws + off;
    off += (bytes + 255) & ~(size_t)255;
    return p;
  };
  float* h = (float*)alloc((size_t)N0 * 512 * 4);      // [N0,512]
  float* as1 = (float*)alloc((size_t)N0 * 4 * 4);      // [N0,4]
  float* ad1v = (float*)alloc((size_t)N1 * 4 * 4);     // [N1,4]
  float* agg1 = (float*)alloc((size_t)N1 * 512 * 4);   // [N1,512]
  float* out2 = (float*)alloc((size_t)N2 * 256 * 4);   // [N2,256]
  int* deg1 = (int*)alloc((size_t)N1 * 4);
  int* offs1 = (int*)alloc((size_t)(N1 + 1) * 4);
  int* cur1 = (int*)alloc((size_t)N1 * 4);
  int* csr1 = (int*)alloc((size_t)E1 * 4);
  int* deg2 = (int*)alloc((size_t)N2 * 4);
  int* offs2 = (int*)alloc((size_t)(N2 + 1) * 4);
  int* cur2 = (int*)alloc((size_t)N2 * 4);
  int* csr2 = (int*)alloc((size_t)E2 * 4);
  float* as2 = (float*)alloc((size_t)N1 * 4);
  float* ad2v = (float*)alloc((size_t)N2 * 4);
  // reuse h region after agg1 consumed it:
  float* hid1 = h;                       // [N1,256]
  float* g2 = h + (size_t)N1 * 256;      // [N1,256]

  hipMemsetAsync(deg1, 0, (size_t)N1 * 4, stream);
  hipMemsetAsync(deg2, 0, (size_t)N2 * 4, stream);

  // h = x @ W1   [N0,512]
  gemm_kernel<false, false><<<dim3(N0 / 64, 512 / 64), 256, 0, stream>>>(
      x, W1, nullptr, h, N0, 512, IN_DIM);
  attn1_kernel<<<N0, 256, 0, stream>>>(h, att_s1, att_d1, as1, ad1v);
  hist_kernel<<<(E1 + 255) / 256, 256, 0, stream>>>(ed1, E1, deg1);
  scan_kernel<<<1, 1024, 0, stream>>>(deg1, N1, offs1, cur1);
  scatter_kernel<<<(E1 + 255) / 256, 256, 0, stream>>>(es1, ed1, E1, cur1, csr1);
  agg1_kernel<<<N1, 256, 0, stream>>>(h, as1, ad1v, offs1, csr1, b1, agg1);
  // hid1 = agg1 @ c1w^T + c1b   [N1,256]
  gemm_kernel<true, true><<<dim3(N1 / 64, 256 / 64), 256, 0, stream>>>(
      agg1, c1w, c1b, hid1, N1, HID_DIM, 512);
  // g2 = hid1 @ W2   [N1,256]
  gemm_kernel<false, false><<<dim3(N1 / 64, 256 / 64), 256, 0, stream>>>(
      hid1, W2, nullptr, g2, N1, HID_DIM, HID_DIM);
  attn2_kernel<<<N1, 256, 0, stream>>>(g2, att_s2, att_d2, as2, ad2v);
  hist_kernel<<<(E2 + 255) / 256, 256, 0, stream>>>(ed2, E2, deg2);
  scan_kernel<<<1, 1024, 0, stream>>>(deg2, N2, offs2, cur2);
  scatter_kernel<<<(E2 + 255) / 256, 256, 0, stream>>>(es2, ed2, E2, cur2, csr2);
  agg2_kernel<<<N2, 256, 0, stream>>>(g2, as2, ad2v, offs2, csr2, b2, out2);
  // out = out2 @ c2w^T + c2b   [N2,128]
  gemm_kernel<true, true><<<dim3(N2 / 64, 128 / 64), 256, 0, stream>>>(
      out2, c2w, c2b, out, N2, OUT_DIM, HID_DIM);
}

// Round 2
// 485.913 us; speedup vs baseline: 2.1203x; 2.1203x over previous
//
#include <hip/hip_runtime.h>
#include <math.h>

#define IN_DIM 128
#define HID_DIM 256
#define OUT_DIM 128
#define HEADS 4
#define N0 80000
#define N1 40000
#define N2 8000
#define E1 400000
#define E2 128000
#define NEG 0.2f

typedef __attribute__((ext_vector_type(8))) short bf16x8;
typedef __attribute__((ext_vector_type(4))) float f32x4;

__device__ __forceinline__ float bf2f(short s) {
  return __uint_as_float(((unsigned int)(unsigned short)s) << 16);
}
__device__ __forceinline__ short f2bf(float f) {
  unsigned int u = __float_as_uint(f);
  unsigned int r = (u + 0x7FFFu + ((u >> 16) & 1u)) >> 16;
  return (short)r;
}

// ---------------- elementwise f32 -> bf16 (n multiple of 4) ----------------
__global__ void f2bf_kernel(const float* __restrict__ in, short* __restrict__ out,
                            long n) {
  long idx = ((long)blockIdx.x * blockDim.x + threadIdx.x) * 4;
  if (idx < n) {
    float4 v = *(const float4*)(in + idx);
    short4 o;
    o.x = f2bf(v.x); o.y = f2bf(v.y); o.z = f2bf(v.z); o.w = f2bf(v.w);
    *(short4*)(out + idx) = o;
  }
}

// ---------------- transpose [K,N] f32 -> [N,K] bf16 ----------------
__global__ void transpose_bf16_kernel(const float* __restrict__ in,
                                      short* __restrict__ out, int K, int N) {
  int i = blockIdx.x * blockDim.x + threadIdx.x;
  if (i < N * K) {
    int r = i / K, c = i % K;  // out[r][c] = in[c][r]
    out[i] = f2bf(in[(long)c * N + r]);
  }
}

// ---------------- bf16 MFMA GEMM: C[M,N] = A[M,K] @ Bt[N,K]^T (+bias) -----
// A bf16 [M,K] row-major, Bt bf16 [N,K] row-major. N mult of 64, K mult of 32.
template<bool BIAS, bool OUTBF>
__global__ __launch_bounds__(256) void mm_bf16_kernel(
    const short* __restrict__ A, const short* __restrict__ Bt,
    const float* __restrict__ bias, void* __restrict__ Cv,
    int M, int N, int K) {
  __shared__ short As[128][40];  // 32 used + 8 pad
  __shared__ short Bs[64][40];
  int tid = threadIdx.x;
  int bn = blockIdx.x * 64;
  int bm = blockIdx.y * 128;
  int w = tid >> 6;        // wave 0..3 -> rows [32w,32w+32)
  int lane = tid & 63;
  int lr = lane & 15, kb = lane >> 4;  // frag row/col, k-group
  f32x4 acc[2][4] = {};

  for (int k0 = 0; k0 < K; k0 += 32) {
    // stage A: 128 rows x 32 bf16 = 512 segs of 8 bf16 (16B)
#pragma unroll
    for (int i = 0; i < 2; i++) {
      int seg = tid + i * 256;
      int row = seg >> 2, part = seg & 3;
      int gm = bm + row;
      bf16x8 v = {0, 0, 0, 0, 0, 0, 0, 0};
      if (gm < M) v = *(const bf16x8*)(A + (long)gm * K + k0 + part * 8);
      *(bf16x8*)&As[row][part * 8] = v;
    }
    // stage B: 64 rows x 32 bf16 = 256 segs
    {
      int r = tid >> 2, part = tid & 3;
      *(bf16x8*)&Bs[r][part * 8] =
          *(const bf16x8*)(Bt + (long)(bn + r) * K + k0 + part * 8);
    }
    __syncthreads();
    bf16x8 a0 = *(const bf16x8*)&As[w * 32 + lr][kb * 8];
    bf16x8 a1 = *(const bf16x8*)&As[w * 32 + 16 + lr][kb * 8];
    bf16x8 b0 = *(const bf16x8*)&Bs[lr][kb * 8];
    bf16x8 b1 = *(const bf16x8*)&Bs[16 + lr][kb * 8];
    bf16x8 b2 = *(const bf16x8*)&Bs[32 + lr][kb * 8];
    bf16x8 b3 = *(const bf16x8*)&Bs[48 + lr][kb * 8];
    acc[0][0] = __builtin_amdgcn_mfma_f32_16x16x32_bf16(a0, b0, acc[0][0], 0, 0, 0);
    acc[0][1] = __builtin_amdgcn_mfma_f32_16x16x32_bf16(a0, b1, acc[0][1], 0, 0, 0);
    acc[0][2] = __builtin_amdgcn_mfma_f32_16x16x32_bf16(a0, b2, acc[0][2], 0, 0, 0);
    acc[0][3] = __builtin_amdgcn_mfma_f32_16x16x32_bf16(a0, b3, acc[0][3], 0, 0, 0);
    acc[1][0] = __builtin_amdgcn_mfma_f32_16x16x32_bf16(a1, b0, acc[1][0], 0, 0, 0);
    acc[1][1] = __builtin_amdgcn_mfma_f32_16x16x32_bf16(a1, b1, acc[1][1], 0, 0, 0);
    acc[1][2] = __builtin_amdgcn_mfma_f32_16x16x32_bf16(a1, b2, acc[1][2], 0, 0, 0);
    acc[1][3] = __builtin_amdgcn_mfma_f32_16x16x32_bf16(a1, b3, acc[1][3], 0, 0, 0);
    __syncthreads();
  }
  // epilogue: row = bm + w*32 + mt*16 + kb*4 + r, col = bn + nt*16 + lr
#pragma unroll
  for (int mt = 0; mt < 2; mt++) {
#pragma unroll
    for (int nt = 0; nt < 4; nt++) {
#pragma unroll
      for (int r = 0; r < 4; r++) {
        int row = bm + w * 32 + mt * 16 + kb * 4 + r;
        if (row >= M) continue;
        int col = bn + nt * 16 + lr;
        float v = acc[mt][nt][r];
        if (BIAS) v += bias[col];
        if (OUTBF)
          ((short*)Cv)[(long)row * N + col] = f2bf(v);
        else
          ((float*)Cv)[(long)row * N + col] = v;
      }
    }
  }
}

// ---------------- attn dots, layer 1 (h bf16 [*,512]) ----------------
__global__ __launch_bounds__(256) void attn1_kernel(
    const short* __restrict__ h, const float* __restrict__ att_s,
    const float* __restrict__ att_d, float* __restrict__ a_s,
    float* __restrict__ a_d) {
  int n = blockIdx.x;
  int tid = threadIdx.x;  // channel c = 2*tid; head = tid>>6
  int c = tid * 2;
  short2 hv = *(const short2*)&h[(long)n * 512 + c];
  float2 as = *(const float2*)&att_s[c];
  float2 ad = *(const float2*)&att_d[c];
  float hx = bf2f(hv.x), hy = bf2f(hv.y);
  float s = hx * as.x + hy * as.y;
  float d = hx * ad.x + hy * ad.y;
  for (int off = 32; off >= 1; off >>= 1) {
    s += __shfl_down(s, off);
    d += __shfl_down(d, off);
  }
  if ((tid & 63) == 0) {
    int hd = tid >> 6;
    a_s[n * 4 + hd] = s;
    if (n < N1) a_d[n * 4 + hd] = d;
  }
}

// ---------------- attn dots, layer 2 (g bf16 [*,256]) ----------------
__global__ __launch_bounds__(256) void attn2_kernel(
    const short* __restrict__ g, const float* __restrict__ att_s,
    const float* __restrict__ att_d, float* __restrict__ a_s,
    float* __restrict__ a_d) {
  __shared__ float red_s[4], red_d[4];
  int n = blockIdx.x;
  int tid = threadIdx.x;
  float hv = bf2f(g[(long)n * 256 + tid]);
  float s = hv * att_s[tid], d = hv * att_d[tid];
  for (int off = 32; off >= 1; off >>= 1) {
    s += __shfl_down(s, off);
    d += __shfl_down(d, off);
  }
  if ((tid & 63) == 0) {
    red_s[tid >> 6] = s;
    red_d[tid >> 6] = d;
  }
  __syncthreads();
  if (tid == 0) {
    a_s[n] = red_s[0] + red_s[1] + red_s[2] + red_s[3];
    if (n < N2) a_d[n] = red_d[0] + red_d[1] + red_d[2] + red_d[3];
  }
}

// ---------------- CSR build ----------------
__global__ void hist_kernel(const int* __restrict__ dst, int E,
                            int* __restrict__ deg) {
  int e = blockIdx.x * blockDim.x + threadIdx.x;
  if (e < E) atomicAdd(&deg[dst[e]], 1);
}

__global__ __launch_bounds__(1024) void scan_kernel(
    const int* __restrict__ deg, int n, int* __restrict__ offs,
    int* __restrict__ cursor) {
  __shared__ int part[1024];
  int tid = threadIdx.x;
  int chunk = (n + 1023) / 1024;
  int lo = tid * chunk, hi = min(n, lo + chunk);
  int s = 0;
  for (int i = lo; i < hi; i++) s += deg[i];
  part[tid] = s;
  __syncthreads();
  for (int off = 1; off < 1024; off <<= 1) {
    int v = (tid >= off) ? part[tid - off] : 0;
    __syncthreads();
    part[tid] += v;
    __syncthreads();
  }
  int base = (tid == 0) ? 0 : part[tid - 1];
  for (int i = lo; i < hi; i++) {
    offs[i] = base;
    cursor[i] = base;
    base += deg[i];
  }
  if (tid == 1023) offs[n] = part[1023];
}

__global__ void scatter_kernel(const int* __restrict__ src,
                               const int* __restrict__ dst, int E,
                               int* __restrict__ cursor,
                               int* __restrict__ csr_src) {
  int e = blockIdx.x * blockDim.x + threadIdx.x;
  if (e < E) {
    int p = atomicAdd(&cursor[dst[e]], 1);
    csr_src[p] = src[e];
  }
}

// ---------------- aggregation layer 1 (heads=4, C=128, h bf16) -----------
__global__ __launch_bounds__(256) void agg1_kernel(
    const short* __restrict__ h, const float* __restrict__ a_s,
    const float* __restrict__ a_d, const int* __restrict__ offs,
    const int* __restrict__ csr_src, const float* __restrict__ b1,
    short* __restrict__ out) {
  int d = blockIdx.x, tid = threadIdx.x;
  __shared__ float s_w[64 * 4];
  __shared__ int s_src[64];
  __shared__ float s_red[16];
  __shared__ float s_m[4], s_den[4];
  int lo = offs[d], deg = offs[d + 1] - lo;
  int hd = tid & 3;
  float ad = a_d[d * 4 + hd];
  // phase 1: per-head max
  float mx = -INFINITY;
  for (int e = tid >> 2; e < deg; e += 64) {
    int src = csr_src[lo + e];
    float t = a_s[src * 4 + hd] + ad;
    t = t > 0.f ? t : NEG * t;
    mx = fmaxf(mx, t);
  }
  for (int off = 4; off <= 32; off <<= 1) mx = fmaxf(mx, __shfl_xor(mx, off));
  if ((tid & 63) < 4) s_red[(tid >> 6) * 4 + hd] = mx;
  __syncthreads();
  if (tid < 4)
    s_m[tid] = fmaxf(fmaxf(s_red[tid], s_red[4 + tid]),
                     fmaxf(s_red[8 + tid], s_red[12 + tid]));
  __syncthreads();
  // phase 2: per-head denom
  float m_h = s_m[hd];
  float sm = 0.f;
  for (int e = tid >> 2; e < deg; e += 64) {
    int src = csr_src[lo + e];
    float t = a_s[src * 4 + hd] + ad;
    t = t > 0.f ? t : NEG * t;
    sm += expf(t - m_h);
  }
  for (int off = 4; off <= 32; off <<= 1) sm += __shfl_xor(sm, off);
  if ((tid & 63) < 4) s_red[(tid >> 6) * 4 + hd] = sm;
  __syncthreads();
  if (tid < 4)
    s_den[tid] = s_red[tid] + s_red[4 + tid] + s_red[8 + tid] + s_red[12 + tid] +
                 1e-16f;
  __syncthreads();
  // phase 3: weighted accumulation, chunked by 64 edges
  int ch = tid * 2;
  int hd2 = ch >> 7;  // = wave id
  float accx = 0.f, accy = 0.f;
  for (int c0 = 0; c0 < deg; c0 += 64) {
    int rem = min(64, deg - c0);
    __syncthreads();
    int eloc = tid >> 2;
    if (eloc < rem) {
      int src = csr_src[lo + c0 + eloc];
      if (hd == 0) s_src[eloc] = src;
      float t = a_s[src * 4 + hd] + ad;
      t = t > 0.f ? t : NEG * t;
      s_w[eloc * 4 + hd] = expf(t - s_m[hd]) / s_den[hd];
    }
    __syncthreads();
    for (int j = 0; j < rem; j++) {
      short2 v = *(const short2*)&h[(long)s_src[j] * 512 + ch];
      float w = s_w[j * 4 + hd2];
      accx += w * bf2f(v.x);
      accy += w * bf2f(v.y);
    }
  }
  out[(long)d * 512 + ch] = f2bf(accx + b1[ch]);
  out[(long)d * 512 + ch + 1] = f2bf(accy + b1[ch + 1]);
}

// ---------------- aggregation layer 2 (heads=1, C=256, g bf16) -----------
__global__ __launch_bounds__(256) void agg2_kernel(
    const short* __restrict__ g, const float* __restrict__ a_s,
    const float* __restrict__ a_d, const int* __restrict__ offs,
    const int* __restrict__ csr_src, const float* __restrict__ b2,
    short* __restrict__ out) {
  int d = blockIdx.x, tid = threadIdx.x;
  __shared__ float s_w[64];
  __shared__ int s_src[64];
  __shared__ float s_red[4];
  int lo = offs[d], deg = offs[d + 1] - lo;
  float ad = a_d[d];
  float mx = -INFINITY;
  for (int e = tid; e < deg; e += 256) {
    float t = a_s[csr_src[lo + e]] + ad;
    t = t > 0.f ? t : NEG * t;
    mx = fmaxf(mx, t);
  }
  for (int off = 32; off >= 1; off >>= 1) mx = fmaxf(mx, __shfl_xor(mx, off));
  if ((tid & 63) == 0) s_red[tid >> 6] = mx;
  __syncthreads();
  mx = fmaxf(fmaxf(s_red[0], s_red[1]), fmaxf(s_red[2], s_red[3]));
  __syncthreads();
  float sm = 0.f;
  for (int e = tid; e < deg; e += 256) {
    float t = a_s[csr_src[lo + e]] + ad;
    t = t > 0.f ? t : NEG * t;
    sm += expf(t - mx);
  }
  for (int off = 32; off >= 1; off >>= 1) sm += __shfl_xor(sm, off);
  if ((tid & 63) == 0) s_red[tid >> 6] = sm;
  __syncthreads();
  float denom = s_red[0] + s_red[1] + s_red[2] + s_red[3] + 1e-16f;
  float acc = 0.f;
  for (int c0 = 0; c0 < deg; c0 += 64) {
    int rem = min(64, deg - c0);
    __syncthreads();
    if (tid < rem) {
      int src = csr_src[lo + c0 + tid];
      s_src[tid] = src;
      float t = a_s[src] + ad;
      t = t > 0.f ? t : NEG * t;
      s_w[tid] = expf(t - mx) / denom;
    }
    __syncthreads();
    for (int j = 0; j < rem; j++)
      acc += s_w[j] * bf2f(g[(long)s_src[j] * 256 + tid]);
  }
  out[(long)d * 256 + tid] = f2bf(acc + b2[tid]);
}

extern "C" void kernel_launch(void* const* d_in, const int* in_sizes, int n_in,
                              void* d_out, int out_size, void* d_ws,
                              size_t ws_size, hipStream_t stream) {
  const float* x = (const float*)d_in[0];
  const int* es1 = (const int*)d_in[1];
  const int* ed1 = (const int*)d_in[2];
  const int* es2 = (const int*)d_in[3];
  const int* ed2 = (const int*)d_in[4];
  const float* W1 = (const float*)d_in[5];
  const float* att_s1 = (const float*)d_in[6];
  const float* att_d1 = (const float*)d_in[7];
  const float* b1 = (const float*)d_in[8];
  const float* W2 = (const float*)d_in[9];
  const float* att_s2 = (const float*)d_in[10];
  const float* att_d2 = (const float*)d_in[11];
  const float* b2 = (const float*)d_in[12];
  const float* c1w = (const float*)d_in[13];
  const float* c1b = (const float*)d_in[14];
  const float* c2w = (const float*)d_in[15];
  const float* c2b = (const float*)d_in[16];
  float* out = (float*)d_out;

  char* ws = (char*)d_ws;
  size_t off = 0;
  auto alloc = [&](size_t bytes) {
    void* p = ws + off;
    off += (bytes + 255) & ~(size_t)255;
    return p;
  };
  short* x_bf = (short*)alloc((size_t)N0 * 128 * 2);
  short* h_bf = (short*)alloc((size_t)N0 * 512 * 2);
  short* agg1_bf = (short*)alloc((size_t)N1 * 512 * 2);
  short* hid1_bf = (short*)alloc((size_t)N1 * 256 * 2);
  short* g2_bf = (short*)alloc((size_t)N1 * 256 * 2);
  short* out2_bf = (short*)alloc((size_t)N2 * 256 * 2);
  short* W1t_bf = (short*)alloc((size_t)512 * 128 * 2);
  short* W2t_bf = (short*)alloc((size_t)256 * 256 * 2);
  short* c1w_bf = (short*)alloc((size_t)256 * 512 * 2);
  short* c2w_bf = (short*)alloc((size_t)128 * 256 * 2);
  float* as1 = (float*)alloc((size_t)N0 * 4 * 4);
  float* ad1v = (float*)alloc((size_t)N1 * 4 * 4);
  float* as2 = (float*)alloc((size_t)N1 * 4);
  float* ad2v = (float*)alloc((size_t)N2 * 4);
  int* deg1 = (int*)alloc((size_t)N1 * 4);
  int* offs1 = (int*)alloc((size_t)(N1 + 1) * 4);
  int* cur1 = (int*)alloc((size_t)N1 * 4);
  int* csr1 = (int*)alloc((size_t)E1 * 4);
  int* deg2 = (int*)alloc((size_t)N2 * 4);
  int* offs2 = (int*)alloc((size_t)(N2 + 1) * 4);
  int* cur2 = (int*)alloc((size_t)N2 * 4);
  int* csr2 = (int*)alloc((size_t)E2 * 4);

  hipMemsetAsync(deg1, 0, (size_t)N1 * 4, stream);
  hipMemsetAsync(deg2, 0, (size_t)N2 * 4, stream);

  // weight prep
  f2bf_kernel<<<(N0 * 128 / 4 + 255) / 256, 256, 0, stream>>>(x, x_bf,
                                                              (long)N0 * 128);
  transpose_bf16_kernel<<<(512 * 128 + 255) / 256, 256, 0, stream>>>(
      W1, W1t_bf, 128, 512);
  transpose_bf16_kernel<<<(256 * 256 + 255) / 256, 256, 0, stream>>>(
      W2, W2t_bf, 256, 256);
  f2bf_kernel<<<(256 * 512 / 4 + 255) / 256, 256, 0, stream>>>(c1w, c1w_bf,
                                                               256 * 512);
  f2bf_kernel<<<(128 * 256 / 4 + 255) / 256, 256, 0, stream>>>(c2w, c2w_bf,
                                                               128 * 256);

  // h = x @ W1   [N0,512] bf16
  mm_bf16_kernel<false, true><<<dim3(512 / 64, (N0 + 127) / 128), 256, 0,
                                stream>>>(x_bf, W1t_bf, nullptr, h_bf, N0, 512,
                                          128);
  attn1_kernel<<<N0, 256, 0, stream>>>(h_bf, att_s1, att_d1, as1, ad1v);
  hist_kernel<<<(E1 + 255) / 256, 256, 0, stream>>>(ed1, E1, deg1);
  scan_kernel<<<1, 1024, 0, stream>>>(deg1, N1, offs1, cur1);
  scatter_kernel<<<(E1 + 255) / 256, 256, 0, stream>>>(es1, ed1, E1, cur1, csr1);
  agg1_kernel<<<N1, 256, 0, stream>>>(h_bf, as1, ad1v, offs1, csr1, b1, agg1_bf);
  // hid1 = agg1 @ c1w^T + c1b   [N1,256]
  mm_bf16_kernel<true, true><<<dim3(256 / 64, (N1 + 127) / 128), 256, 0,
                               stream>>>(agg1_bf, c1w_bf, c1b, hid1_bf, N1, 256,
                                         512);
  // g2 = hid1 @ W2   [N1,256]
  mm_bf16_kernel<false, true><<<dim3(256 / 64, (N1 + 127) / 128), 256, 0,
                                stream>>>(hid1_bf, W2t_bf, nullptr, g2_bf, N1,
                                          256, 256);
  attn2_kernel<<<N1, 256, 0, stream>>>(g2_bf, att_s2, att_d2, as2, ad2v);
  hist_kernel<<<(E2 + 255) / 256, 256, 0, stream>>>(ed2, E2, deg2);
  scan_kernel<<<1, 1024, 0, stream>>>(deg2, N2, offs2, cur2);
  scatter_kernel<<<(E2 + 255) / 256, 256, 0, stream>>>(es2, ed2, E2, cur2, csr2);
  agg2_kernel<<<N2, 256, 0, stream>>>(g2_bf, as2, ad2v, offs2, csr2, b2,
                                      out2_bf);
  // out = out2 @ c2w^T + c2b   [N2,128] f32
  mm_bf16_kernel<true, false><<<dim3(128 / 64, (N2 + 127) / 128), 256, 0,
                                stream>>>(out2_bf, c2w_bf, c2b, out, N2, 128,
                                          256);
}

// Round 3
// 430.099 us; speedup vs baseline: 2.3955x; 1.1298x over previous
//
#include <hip/hip_runtime.h>
#include <math.h>

#define IN_DIM 128
#define HID_DIM 256
#define OUT_DIM 128
#define HEADS 4
#define N0 80000
#define N1 40000
#define N2 8000
#define E1 400000
#define E2 128000
#define NEG 0.2f

typedef __attribute__((ext_vector_type(8))) short bf16x8;
typedef __attribute__((ext_vector_type(4))) float f32x4;

__device__ __forceinline__ float bf2f(short s) {
  return __uint_as_float(((unsigned int)(unsigned short)s) << 16);
}
__device__ __forceinline__ short f2bf(float f) {
  unsigned int u = __float_as_uint(f);
  unsigned int r = (u + 0x7FFFu + ((u >> 16) & 1u)) >> 16;
  return (short)r;
}

// ---------------- elementwise f32 -> bf16 (n multiple of 4) ----------------
__global__ void f2bf_kernel(const float* __restrict__ in, short* __restrict__ out,
                            long n) {
  long idx = ((long)blockIdx.x * blockDim.x + threadIdx.x) * 4;
  if (idx < n) {
    float4 v = *(const float4*)(in + idx);
    short4 o;
    o.x = f2bf(v.x); o.y = f2bf(v.y); o.z = f2bf(v.z); o.w = f2bf(v.w);
    *(short4*)(out + idx) = o;
  }
}

// ---------------- transpose [K,N] f32 -> [N,K] bf16 ----------------
__global__ void transpose_bf16_kernel(const float* __restrict__ in,
                                      short* __restrict__ out, int K, int N) {
  int i = blockIdx.x * blockDim.x + threadIdx.x;
  if (i < N * K) {
    int r = i / K, c = i % K;  // out[r][c] = in[c][r]
    out[i] = f2bf(in[(long)c * N + r]);
  }
}

// ---------------- bf16 MFMA GEMM: C[M,N] = A[M,K] @ Bt[N,K]^T (+bias) -----
// A bf16 [M,K] row-major, Bt bf16 [N,K] row-major. N mult of 64, K mult of 32.
template<bool BIAS, bool OUTBF>
__global__ __launch_bounds__(256) void mm_bf16_kernel(
    const short* __restrict__ A, const short* __restrict__ Bt,
    const float* __restrict__ bias, void* __restrict__ Cv,
    int M, int N, int K) {
  __shared__ short As[128][40];  // 32 used + 8 pad
  __shared__ short Bs[64][40];
  int tid = threadIdx.x;
  int bn = blockIdx.x * 64;
  int bm = blockIdx.y * 128;
  int w = tid >> 6;        // wave 0..3 -> rows [32w,32w+32)
  int lane = tid & 63;
  int lr = lane & 15, kb = lane >> 4;  // frag row/col, k-group
  f32x4 acc[2][4] = {};

  for (int k0 = 0; k0 < K; k0 += 32) {
    // stage A: 128 rows x 32 bf16 = 512 segs of 8 bf16 (16B)
#pragma unroll
    for (int i = 0; i < 2; i++) {
      int seg = tid + i * 256;
      int row = seg >> 2, part = seg & 3;
      int gm = bm + row;
      bf16x8 v = {0, 0, 0, 0, 0, 0, 0, 0};
      if (gm < M) v = *(const bf16x8*)(A + (long)gm * K + k0 + part * 8);
      *(bf16x8*)&As[row][part * 8] = v;
    }
    // stage B: 64 rows x 32 bf16 = 256 segs
    {
      int r = tid >> 2, part = tid & 3;
      *(bf16x8*)&Bs[r][part * 8] =
          *(const bf16x8*)(Bt + (long)(bn + r) * K + k0 + part * 8);
    }
    __syncthreads();
    bf16x8 a0 = *(const bf16x8*)&As[w * 32 + lr][kb * 8];
    bf16x8 a1 = *(const bf16x8*)&As[w * 32 + 16 + lr][kb * 8];
    bf16x8 b0 = *(const bf16x8*)&Bs[lr][kb * 8];
    bf16x8 b1 = *(const bf16x8*)&Bs[16 + lr][kb * 8];
    bf16x8 b2 = *(const bf16x8*)&Bs[32 + lr][kb * 8];
    bf16x8 b3 = *(const bf16x8*)&Bs[48 + lr][kb * 8];
    acc[0][0] = __builtin_amdgcn_mfma_f32_16x16x32_bf16(a0, b0, acc[0][0], 0, 0, 0);
    acc[0][1] = __builtin_amdgcn_mfma_f32_16x16x32_bf16(a0, b1, acc[0][1], 0, 0, 0);
    acc[0][2] = __builtin_amdgcn_mfma_f32_16x16x32_bf16(a0, b2, acc[0][2], 0, 0, 0);
    acc[0][3] = __builtin_amdgcn_mfma_f32_16x16x32_bf16(a0, b3, acc[0][3], 0, 0, 0);
    acc[1][0] = __builtin_amdgcn_mfma_f32_16x16x32_bf16(a1, b0, acc[1][0], 0, 0, 0);
    acc[1][1] = __builtin_amdgcn_mfma_f32_16x16x32_bf16(a1, b1, acc[1][1], 0, 0, 0);
    acc[1][2] = __builtin_amdgcn_mfma_f32_16x16x32_bf16(a1, b2, acc[1][2], 0, 0, 0);
    acc[1][3] = __builtin_amdgcn_mfma_f32_16x16x32_bf16(a1, b3, acc[1][3], 0, 0, 0);
    __syncthreads();
  }
  // epilogue: row = bm + w*32 + mt*16 + kb*4 + r, col = bn + nt*16 + lr
#pragma unroll
  for (int mt = 0; mt < 2; mt++) {
#pragma unroll
    for (int nt = 0; nt < 4; nt++) {
#pragma unroll
      for (int r = 0; r < 4; r++) {
        int row = bm + w * 32 + mt * 16 + kb * 4 + r;
        if (row >= M) continue;
        int col = bn + nt * 16 + lr;
        float v = acc[mt][nt][r];
        if (BIAS) v += bias[col];
        if (OUTBF)
          ((short*)Cv)[(long)row * N + col] = f2bf(v);
        else
          ((float*)Cv)[(long)row * N + col] = v;
      }
    }
  }
}

// ---------------- attn dots, layer 1: wave per node ----------------
__global__ __launch_bounds__(256) void attn1_kernel(
    const short* __restrict__ h, const float* __restrict__ att_s,
    const float* __restrict__ att_d, float* __restrict__ a_s,
    float* __restrict__ a_d) {
  int wid = threadIdx.x >> 6, lane = threadIdx.x & 63;
  long n = (long)blockIdx.x * 4 + wid;
  if (n >= N0) return;
  int ch0 = lane * 8;
  bf16x8 hv = *(const bf16x8*)&h[n * 512 + ch0];
  float4 asa = *(const float4*)&att_s[ch0];
  float4 asb = *(const float4*)&att_s[ch0 + 4];
  float4 ada = *(const float4*)&att_d[ch0];
  float4 adb = *(const float4*)&att_d[ch0 + 4];
  float hf[8];
#pragma unroll
  for (int k = 0; k < 8; k++) hf[k] = bf2f(hv[k]);
  float s = hf[0] * asa.x + hf[1] * asa.y + hf[2] * asa.z + hf[3] * asa.w +
            hf[4] * asb.x + hf[5] * asb.y + hf[6] * asb.z + hf[7] * asb.w;
  float d = hf[0] * ada.x + hf[1] * ada.y + hf[2] * ada.z + hf[3] * ada.w +
            hf[4] * adb.x + hf[5] * adb.y + hf[6] * adb.z + hf[7] * adb.w;
#pragma unroll
  for (int off = 1; off <= 8; off <<= 1) {
    s += __shfl_xor(s, off);
    d += __shfl_xor(d, off);
  }
  if ((lane & 15) == 0) {
    int hd = lane >> 4;
    a_s[n * 4 + hd] = s;
    if (n < N1) a_d[n * 4 + hd] = d;
  }
}

// ---------------- attn dots, layer 2: wave per node ----------------
__global__ __launch_bounds__(256) void attn2_kernel(
    const short* __restrict__ g, const float* __restrict__ att_s,
    const float* __restrict__ att_d, float* __restrict__ a_s,
    float* __restrict__ a_d) {
  int wid = threadIdx.x >> 6, lane = threadIdx.x & 63;
  long n = (long)blockIdx.x * 4 + wid;
  if (n >= N1) return;
  int c0 = lane * 4;
  short4 gv = *(const short4*)&g[n * 256 + c0];
  float4 as = *(const float4*)&att_s[c0];
  float4 ad4 = *(const float4*)&att_d[c0];
  float g0 = bf2f(gv.x), g1 = bf2f(gv.y), g2v = bf2f(gv.z), g3 = bf2f(gv.w);
  float s = g0 * as.x + g1 * as.y + g2v * as.z + g3 * as.w;
  float d = g0 * ad4.x + g1 * ad4.y + g2v * ad4.z + g3 * ad4.w;
#pragma unroll
  for (int off = 1; off <= 32; off <<= 1) {
    s += __shfl_xor(s, off);
    d += __shfl_xor(d, off);
  }
  if (lane == 0) {
    a_s[n] = s;
    if (n < N2) a_d[n] = d;
  }
}

// ---------------- CSR build ----------------
__global__ void hist_kernel(const int* __restrict__ dst, int E,
                            int* __restrict__ deg) {
  int e = blockIdx.x * blockDim.x + threadIdx.x;
  if (e < E) atomicAdd(&deg[dst[e]], 1);
}

__global__ __launch_bounds__(1024) void scan_kernel(
    const int* __restrict__ deg, int n, int* __restrict__ offs,
    int* __restrict__ cursor) {
  __shared__ int part[1024];
  int tid = threadIdx.x;
  int chunk = (n + 1023) / 1024;
  int lo = tid * chunk, hi = min(n, lo + chunk);
  int s = 0;
  for (int i = lo; i < hi; i++) s += deg[i];
  part[tid] = s;
  __syncthreads();
  for (int off = 1; off < 1024; off <<= 1) {
    int v = (tid >= off) ? part[tid - off] : 0;
    __syncthreads();
    part[tid] += v;
    __syncthreads();
  }
  int base = (tid == 0) ? 0 : part[tid - 1];
  for (int i = lo; i < hi; i++) {
    offs[i] = base;
    cursor[i] = base;
    base += deg[i];
  }
  if (tid == 1023) offs[n] = part[1023];
}

__global__ void scatter_kernel(const int* __restrict__ src,
                               const int* __restrict__ dst, int E,
                               int* __restrict__ cursor,
                               int* __restrict__ csr_src) {
  int e = blockIdx.x * blockDim.x + threadIdx.x;
  if (e < E) {
    int p = atomicAdd(&cursor[dst[e]], 1);
    csr_src[p] = src[e];
  }
}

// ------- aggregation layer 1 (heads=4, C=128, h bf16, wave-parallel) ------
__global__ __launch_bounds__(256) void agg1_kernel(
    const short* __restrict__ h, const float* __restrict__ a_s,
    const float* __restrict__ a_d, const int* __restrict__ offs,
    const int* __restrict__ csr_src, const float* __restrict__ b1,
    short* __restrict__ out) {
  int d = blockIdx.x, tid = threadIdx.x;
  int wid = tid >> 6, lane = tid & 63;
  __shared__ float s_w[64 * 4];
  __shared__ int s_src[64];
  __shared__ float s_red[16];
  __shared__ float s_m[4], s_den[4];
  __shared__ float s_acc[4][512];
  int lo = offs[d], deg = offs[d + 1] - lo;
  int hd = tid & 3;
  float ad = a_d[d * 4 + hd];
  // phase 1: per-head max (thread -> edge tid>>2, head tid&3)
  float mx = -INFINITY;
  for (int e = tid >> 2; e < deg; e += 64) {
    int src = csr_src[lo + e];
    float t = a_s[src * 4 + hd] + ad;
    t = t > 0.f ? t : NEG * t;
    mx = fmaxf(mx, t);
  }
#pragma unroll
  for (int off = 4; off <= 32; off <<= 1) mx = fmaxf(mx, __shfl_xor(mx, off));
  if ((tid & 63) < 4) s_red[wid * 4 + hd] = mx;
  __syncthreads();
  if (tid < 4)
    s_m[tid] = fmaxf(fmaxf(s_red[tid], s_red[4 + tid]),
                     fmaxf(s_red[8 + tid], s_red[12 + tid]));
  __syncthreads();
  // phase 2: per-head denom
  float m_h = s_m[hd];
  float sm = 0.f;
  for (int e = tid >> 2; e < deg; e += 64) {
    int src = csr_src[lo + e];
    float t = a_s[src * 4 + hd] + ad;
    t = t > 0.f ? t : NEG * t;
    sm += expf(t - m_h);
  }
#pragma unroll
  for (int off = 4; off <= 32; off <<= 1) sm += __shfl_xor(sm, off);
  if ((tid & 63) < 4) s_red[wid * 4 + hd] = sm;
  __syncthreads();
  if (tid < 4)
    s_den[tid] = s_red[tid] + s_red[4 + tid] + s_red[8 + tid] + s_red[12 + tid] +
                 1e-16f;
  __syncthreads();
  // phase 3: wave-parallel weighted accumulation, 8 ch per lane
  int ch0 = lane * 8;       // lane covers channels [ch0, ch0+8)
  int headc = lane >> 4;    // head of those channels
  float acc[8] = {};
  for (int c0 = 0; c0 < deg; c0 += 64) {
    int rem = min(64, deg - c0);
    __syncthreads();
    int eloc = tid >> 2;
    if (eloc < rem) {
      int src = csr_src[lo + c0 + eloc];
      if (hd == 0) s_src[eloc] = src;
      float t = a_s[src * 4 + hd] + ad;
      t = t > 0.f ? t : NEG * t;
      s_w[eloc * 4 + hd] = expf(t - s_m[hd]) / s_den[hd];
    }
    __syncthreads();
    for (int j = wid; j < rem; j += 4) {
      int src = s_src[j];
      float w = s_w[j * 4 + headc];
      bf16x8 v = *(const bf16x8*)&h[(long)src * 512 + ch0];
#pragma unroll
      for (int k = 0; k < 8; k++) acc[k] += w * bf2f(v[k]);
    }
  }
#pragma unroll
  for (int k = 0; k < 8; k++) s_acc[wid][ch0 + k] = acc[k];
  __syncthreads();
  int ch = tid * 2;
#pragma unroll
  for (int u = 0; u < 2; u++) {
    int c = ch + u;
    float v = s_acc[0][c] + s_acc[1][c] + s_acc[2][c] + s_acc[3][c] + b1[c];
    out[(long)d * 512 + c] = f2bf(v);
  }
}

// ------- aggregation layer 2 (heads=1, C=256, g bf16, group-parallel) -----
__global__ __launch_bounds__(256) void agg2_kernel(
    const short* __restrict__ g, const float* __restrict__ a_s,
    const float* __restrict__ a_d, const int* __restrict__ offs,
    const int* __restrict__ csr_src, const float* __restrict__ b2,
    short* __restrict__ out) {
  int d = blockIdx.x, tid = threadIdx.x;
  int g8 = tid >> 5, l32 = tid & 31;
  __shared__ float s_w[64];
  __shared__ int s_src[64];
  __shared__ float s_red[4];
  __shared__ float s_acc[8][256];
  int lo = offs[d], deg = offs[d + 1] - lo;
  float ad = a_d[d];
  float mx = -INFINITY;
  for (int e = tid; e < deg; e += 256) {
    float t = a_s[csr_src[lo + e]] + ad;
    t = t > 0.f ? t : NEG * t;
    mx = fmaxf(mx, t);
  }
#pragma unroll
  for (int off = 32; off >= 1; off >>= 1) mx = fmaxf(mx, __shfl_xor(mx, off));
  if ((tid & 63) == 0) s_red[tid >> 6] = mx;
  __syncthreads();
  mx = fmaxf(fmaxf(s_red[0], s_red[1]), fmaxf(s_red[2], s_red[3]));
  __syncthreads();
  float sm = 0.f;
  for (int e = tid; e < deg; e += 256) {
    float t = a_s[csr_src[lo + e]] + ad;
    t = t > 0.f ? t : NEG * t;
    sm += expf(t - mx);
  }
#pragma unroll
  for (int off = 32; off >= 1; off >>= 1) sm += __shfl_xor(sm, off);
  if ((tid & 63) == 0) s_red[tid >> 6] = sm;
  __syncthreads();
  float denom = s_red[0] + s_red[1] + s_red[2] + s_red[3] + 1e-16f;
  int ch0 = l32 * 8;
  float acc[8] = {};
  for (int c0 = 0; c0 < deg; c0 += 64) {
    int rem = min(64, deg - c0);
    __syncthreads();
    if (tid < rem) {
      int src = csr_src[lo + c0 + tid];
      s_src[tid] = src;
      float t = a_s[src] + ad;
      t = t > 0.f ? t : NEG * t;
      s_w[tid] = expf(t - mx) / denom;
    }
    __syncthreads();
    for (int j = g8; j < rem; j += 8) {
      int src = s_src[j];
      float w = s_w[j];
      bf16x8 v = *(const bf16x8*)&g[(long)src * 256 + ch0];
#pragma unroll
      for (int k = 0; k < 8; k++) acc[k] += w * bf2f(v[k]);
    }
  }
#pragma unroll
  for (int k = 0; k < 8; k++) s_acc[g8][ch0 + k] = acc[k];
  __syncthreads();
  float v = 0.f;
#pragma unroll
  for (int q = 0; q < 8; q++) v += s_acc[q][tid];
  out[(long)d * 256 + tid] = f2bf(v + b2[tid]);
}

extern "C" void kernel_launch(void* const* d_in, const int* in_sizes, int n_in,
                              void* d_out, int out_size, void* d_ws,
                              size_t ws_size, hipStream_t stream) {
  const float* x = (const float*)d_in[0];
  const int* es1 = (const int*)d_in[1];
  const int* ed1 = (const int*)d_in[2];
  const int* es2 = (const int*)d_in[3];
  const int* ed2 = (const int*)d_in[4];
  const float* W1 = (const float*)d_in[5];
  const float* att_s1 = (const float*)d_in[6];
  const float* att_d1 = (const float*)d_in[7];
  const float* b1 = (const float*)d_in[8];
  const float* W2 = (const float*)d_in[9];
  const float* att_s2 = (const float*)d_in[10];
  const float* att_d2 = (const float*)d_in[11];
  const float* b2 = (const float*)d_in[12];
  const float* c1w = (const float*)d_in[13];
  const float* c1b = (const float*)d_in[14];
  const float* c2w = (const float*)d_in[15];
  const float* c2b = (const float*)d_in[16];
  float* out = (float*)d_out;

  char* ws = (char*)d_ws;
  size_t off = 0;
  auto alloc = [&](size_t bytes) {
    void* p = ws + off;
    off += (bytes + 255) & ~(size_t)255;
    return p;
  };
  short* x_bf = (short*)alloc((size_t)N0 * 128 * 2);
  short* h_bf = (short*)alloc((size_t)N0 * 512 * 2);
  short* agg1_bf = (short*)alloc((size_t)N1 * 512 * 2);
  short* hid1_bf = (short*)alloc((size_t)N1 * 256 * 2);
  short* g2_bf = (short*)alloc((size_t)N1 * 256 * 2);
  short* out2_bf = (short*)alloc((size_t)N2 * 256 * 2);
  short* W1t_bf = (short*)alloc((size_t)512 * 128 * 2);
  short* W2t_bf = (short*)alloc((size_t)256 * 256 * 2);
  short* c1w_bf = (short*)alloc((size_t)256 * 512 * 2);
  short* c2w_bf = (short*)alloc((size_t)128 * 256 * 2);
  float* as1 = (float*)alloc((size_t)N0 * 4 * 4);
  float* ad1v = (float*)alloc((size_t)N1 * 4 * 4);
  float* as2 = (float*)alloc((size_t)N1 * 4);
  float* ad2v = (float*)alloc((size_t)N2 * 4);
  int* deg1 = (int*)alloc((size_t)N1 * 4);
  int* offs1 = (int*)alloc((size_t)(N1 + 1) * 4);
  int* cur1 = (int*)alloc((size_t)N1 * 4);
  int* csr1 = (int*)alloc((size_t)E1 * 4);
  int* deg2 = (int*)alloc((size_t)N2 * 4);
  int* offs2 = (int*)alloc((size_t)(N2 + 1) * 4);
  int* cur2 = (int*)alloc((size_t)N2 * 4);
  int* csr2 = (int*)alloc((size_t)E2 * 4);

  hipMemsetAsync(deg1, 0, (size_t)N1 * 4, stream);
  hipMemsetAsync(deg2, 0, (size_t)N2 * 4, stream);

  // weight prep
  f2bf_kernel<<<(N0 * 128 / 4 + 255) / 256, 256, 0, stream>>>(x, x_bf,
                                                              (long)N0 * 128);
  transpose_bf16_kernel<<<(512 * 128 + 255) / 256, 256, 0, stream>>>(
      W1, W1t_bf, 128, 512);
  transpose_bf16_kernel<<<(256 * 256 + 255) / 256, 256, 0, stream>>>(
      W2, W2t_bf, 256, 256);
  f2bf_kernel<<<(256 * 512 / 4 + 255) / 256, 256, 0, stream>>>(c1w, c1w_bf,
                                                               256 * 512);
  f2bf_kernel<<<(128 * 256 / 4 + 255) / 256, 256, 0, stream>>>(c2w, c2w_bf,
                                                               128 * 256);

  // h = x @ W1   [N0,512] bf16
  mm_bf16_kernel<false, true><<<dim3(512 / 64, (N0 + 127) / 128), 256, 0,
                                stream>>>(x_bf, W1t_bf, nullptr, h_bf, N0, 512,
                                          128);
  attn1_kernel<<<(N0 + 3) / 4, 256, 0, stream>>>(h_bf, att_s1, att_d1, as1,
                                                 ad1v);
  hist_kernel<<<(E1 + 255) / 256, 256, 0, stream>>>(ed1, E1, deg1);
  scan_kernel<<<1, 1024, 0, stream>>>(deg1, N1, offs1, cur1);
  scatter_kernel<<<(E1 + 255) / 256, 256, 0, stream>>>(es1, ed1, E1, cur1, csr1);
  agg1_kernel<<<N1, 256, 0, stream>>>(h_bf, as1, ad1v, offs1, csr1, b1, agg1_bf);
  // hid1 = agg1 @ c1w^T + c1b   [N1,256]
  mm_bf16_kernel<true, true><<<dim3(256 / 64, (N1 + 127) / 128), 256, 0,
                               stream>>>(agg1_bf, c1w_bf, c1b, hid1_bf, N1, 256,
                                         512);
  // g2 = hid1 @ W2   [N1,256]
  mm_bf16_kernel<false, true><<<dim3(256 / 64, (N1 + 127) / 128), 256, 0,
                                stream>>>(hid1_bf, W2t_bf, nullptr, g2_bf, N1,
                                          256, 256);
  attn2_kernel<<<(N1 + 3) / 4, 256, 0, stream>>>(g2_bf, att_s2, att_d2, as2,
                                                 ad2v);
  hist_kernel<<<(E2 + 255) / 256, 256, 0, stream>>>(ed2, E2, deg2);
  scan_kernel<<<1, 1024, 0, stream>>>(deg2, N2, offs2, cur2);
  scatter_kernel<<<(E2 + 255) / 256, 256, 0, stream>>>(es2, ed2, E2, cur2, csr2);
  agg2_kernel<<<N2, 256, 0, stream>>>(g2_bf, as2, ad2v, offs2, csr2, b2,
                                      out2_bf);
  // out = out2 @ c2w^T + c2b   [N2,128] f32
  mm_bf16_kernel<true, false><<<dim3(128 / 64, (N2 + 127) / 128), 256, 0,
                                stream>>>(out2_bf, c2w_bf, c2b, out, N2, 128,
                                          256);
}

// Round 4
// 429.619 us; speedup vs baseline: 2.3982x; 1.0011x over previous
//
#include <hip/hip_runtime.h>
#include <math.h>

#define IN_DIM 128
#define HID_DIM 256
#define OUT_DIM 128
#define HEADS 4
#define N0 80000
#define N1 40000
#define N2 8000
#define E1 400000
#define E2 128000
#define NEG 0.2f

typedef __attribute__((ext_vector_type(8))) short bf16x8;
typedef __attribute__((ext_vector_type(4))) float f32x4;

__device__ __forceinline__ float bf2f(short s) {
  return __uint_as_float(((unsigned int)(unsigned short)s) << 16);
}
__device__ __forceinline__ short f2bf(float f) {
  unsigned int u = __float_as_uint(f);
  unsigned int r = (u + 0x7FFFu + ((u >> 16) & 1u)) >> 16;
  return (short)r;
}
__device__ __forceinline__ float lrelu(float t) {
  return t > 0.f ? t : NEG * t;
}

// ---------------- elementwise f32 -> bf16 (n multiple of 4) ----------------
__global__ void f2bf_kernel(const float* __restrict__ in, short* __restrict__ out,
                            long n) {
  long idx = ((long)blockIdx.x * blockDim.x + threadIdx.x) * 4;
  if (idx < n) {
    float4 v = *(const float4*)(in + idx);
    short4 o;
    o.x = f2bf(v.x); o.y = f2bf(v.y); o.z = f2bf(v.z); o.w = f2bf(v.w);
    *(short4*)(out + idx) = o;
  }
}

// ------------- prep: p1[i][hh] = sum_c W1[i, h*128+c] * att[h][c] ----------
// hh<4 -> att_src1 head hh ; hh>=4 -> att_dst1 head hh-4.  p1 f32 [128][8]
__global__ void prep_p1_kernel(const float* __restrict__ W1,
                               const float* __restrict__ att_s,
                               const float* __restrict__ att_d,
                               float* __restrict__ p1) {
  int g = blockIdx.x * blockDim.x + threadIdx.x;  // 1024
  if (g >= 128 * 8) return;
  int i = g >> 3, hh = g & 7;
  int h = hh & 3;
  const float* att = (hh < 4) ? att_s : att_d;
  float acc = 0.f;
  for (int c = 0; c < 128; c++)
    acc += W1[(long)i * 512 + h * 128 + c] * att[h * 128 + c];
  p1[g] = acc;
}

// --- prep: M1t[o][kf] = sum_c W1[k, h*128+c] * c1w[o, h*128+c], kf=h*128+k --
__global__ void prep_M1t_kernel(const float* __restrict__ W1,
                                const float* __restrict__ c1w,
                                short* __restrict__ M1t) {
  int g = blockIdx.x * blockDim.x + threadIdx.x;  // 256*512
  if (g >= 256 * 512) return;
  int o = g >> 9, kf = g & 511;
  int h = kf >> 7, k = kf & 127;
  float acc = 0.f;
  for (int c = 0; c < 128; c++)
    acc += W1[(long)k * 512 + h * 128 + c] * c1w[(long)o * 512 + h * 128 + c];
  M1t[g] = f2bf(acc);
}

// ------------- prep: bias1p[o] = c1b[o] + sum_c b1[c]*c1w[o,c] -------------
__global__ void prep_bias1_kernel(const float* __restrict__ b1,
                                  const float* __restrict__ c1w,
                                  const float* __restrict__ c1b,
                                  float* __restrict__ bias1p) {
  int o = blockIdx.x * blockDim.x + threadIdx.x;
  if (o >= 256) return;
  float acc = c1b[o];
  for (int c = 0; c < 512; c++) acc += b1[c] * c1w[(long)o * 512 + c];
  bias1p[o] = acc;
}

// ------------- prep: p2[k][j] = sum_c W2[k,c]*att2_j[c]  (f32 [256][2]) ----
__global__ void prep_p2_kernel(const float* __restrict__ W2,
                               const float* __restrict__ att_s,
                               const float* __restrict__ att_d,
                               float* __restrict__ p2) {
  int g = blockIdx.x * blockDim.x + threadIdx.x;  // 512
  if (g >= 512) return;
  int k = g >> 1, j = g & 1;
  const float* att = j ? att_d : att_s;
  float acc = 0.f;
  for (int c = 0; c < 256; c++) acc += W2[(long)k * 256 + c] * att[c];
  p2[g] = acc;
}

// ------------- prep: M2t[o][k] = sum_c W2[k,c]*c2w[o,c]  (bf16) ------------
__global__ void prep_M2t_kernel(const float* __restrict__ W2,
                                const float* __restrict__ c2w,
                                short* __restrict__ M2t) {
  int g = blockIdx.x * blockDim.x + threadIdx.x;  // 128*256
  if (g >= 128 * 256) return;
  int o = g >> 8, k = g & 255;
  float acc = 0.f;
  for (int c = 0; c < 256; c++)
    acc += W2[(long)k * 256 + c] * c2w[(long)o * 256 + c];
  M2t[g] = f2bf(acc);
}

__global__ void prep_bias2_kernel(const float* __restrict__ b2,
                                  const float* __restrict__ c2w,
                                  const float* __restrict__ c2b,
                                  float* __restrict__ bias2p) {
  int o = blockIdx.x * blockDim.x + threadIdx.x;
  if (o >= 128) return;
  float acc = c2b[o];
  for (int c = 0; c < 256; c++) acc += b2[c] * c2w[(long)o * 256 + c];
  bias2p[o] = acc;
}

// ---------------- bf16 MFMA GEMM: C[M,N] = A[M,K] @ Bt[N,K]^T (+bias) -----
template<bool BIAS, bool OUTBF>
__global__ __launch_bounds__(256) void mm_bf16_kernel(
    const short* __restrict__ A, const short* __restrict__ Bt,
    const float* __restrict__ bias, void* __restrict__ Cv,
    int M, int N, int K) {
  __shared__ short As[128][40];
  __shared__ short Bs[64][40];
  int tid = threadIdx.x;
  int bn = blockIdx.x * 64;
  int bm = blockIdx.y * 128;
  int w = tid >> 6;
  int lane = tid & 63;
  int lr = lane & 15, kb = lane >> 4;
  f32x4 acc[2][4] = {};

  for (int k0 = 0; k0 < K; k0 += 32) {
#pragma unroll
    for (int i = 0; i < 2; i++) {
      int seg = tid + i * 256;
      int row = seg >> 2, part = seg & 3;
      int gm = bm + row;
      bf16x8 v = {0, 0, 0, 0, 0, 0, 0, 0};
      if (gm < M) v = *(const bf16x8*)(A + (long)gm * K + k0 + part * 8);
      *(bf16x8*)&As[row][part * 8] = v;
    }
    {
      int r = tid >> 2, part = tid & 3;
      *(bf16x8*)&Bs[r][part * 8] =
          *(const bf16x8*)(Bt + (long)(bn + r) * K + k0 + part * 8);
    }
    __syncthreads();
    bf16x8 a0 = *(const bf16x8*)&As[w * 32 + lr][kb * 8];
    bf16x8 a1 = *(const bf16x8*)&As[w * 32 + 16 + lr][kb * 8];
    bf16x8 b0 = *(const bf16x8*)&Bs[lr][kb * 8];
    bf16x8 b1 = *(const bf16x8*)&Bs[16 + lr][kb * 8];
    bf16x8 b2 = *(const bf16x8*)&Bs[32 + lr][kb * 8];
    bf16x8 b3 = *(const bf16x8*)&Bs[48 + lr][kb * 8];
    acc[0][0] = __builtin_amdgcn_mfma_f32_16x16x32_bf16(a0, b0, acc[0][0], 0, 0, 0);
    acc[0][1] = __builtin_amdgcn_mfma_f32_16x16x32_bf16(a0, b1, acc[0][1], 0, 0, 0);
    acc[0][2] = __builtin_amdgcn_mfma_f32_16x16x32_bf16(a0, b2, acc[0][2], 0, 0, 0);
    acc[0][3] = __builtin_amdgcn_mfma_f32_16x16x32_bf16(a0, b3, acc[0][3], 0, 0, 0);
    acc[1][0] = __builtin_amdgcn_mfma_f32_16x16x32_bf16(a1, b0, acc[1][0], 0, 0, 0);
    acc[1][1] = __builtin_amdgcn_mfma_f32_16x16x32_bf16(a1, b1, acc[1][1], 0, 0, 0);
    acc[1][2] = __builtin_amdgcn_mfma_f32_16x16x32_bf16(a1, b2, acc[1][2], 0, 0, 0);
    acc[1][3] = __builtin_amdgcn_mfma_f32_16x16x32_bf16(a1, b3, acc[1][3], 0, 0, 0);
    __syncthreads();
  }
#pragma unroll
  for (int mt = 0; mt < 2; mt++) {
#pragma unroll
    for (int nt = 0; nt < 4; nt++) {
#pragma unroll
      for (int r = 0; r < 4; r++) {
        int row = bm + w * 32 + mt * 16 + kb * 4 + r;
        if (row >= M) continue;
        int col = bn + nt * 16 + lr;
        float v = acc[mt][nt][r];
        if (BIAS) v += bias[col];
        if (OUTBF)
          ((short*)Cv)[(long)row * N + col] = f2bf(v);
        else
          ((float*)Cv)[(long)row * N + col] = v;
      }
    }
  }
}

// ---------- attn1: a_s1[n,h]=x[n]·p1[:,h], a_d1[n,h]=x[n]·p1[:,4+h] --------
__global__ __launch_bounds__(256) void attn1_kernel(
    const short* __restrict__ x, const float* __restrict__ p1,
    float* __restrict__ a_s, float* __restrict__ a_d) {
  int wid = threadIdx.x >> 6, lane = threadIdx.x & 63;
  long n = (long)blockIdx.x * 4 + wid;
  if (n >= N0) return;
  short2 xv = *(const short2*)&x[n * 128 + lane * 2];
  float fx = bf2f(xv.x), fy = bf2f(xv.y);
  float4 pa0 = *(const float4*)&p1[(lane * 2) * 8];
  float4 pa1 = *(const float4*)&p1[(lane * 2) * 8 + 4];
  float4 pb0 = *(const float4*)&p1[(lane * 2 + 1) * 8];
  float4 pb1 = *(const float4*)&p1[(lane * 2 + 1) * 8 + 4];
  float acc[8];
  acc[0] = fx * pa0.x + fy * pb0.x;
  acc[1] = fx * pa0.y + fy * pb0.y;
  acc[2] = fx * pa0.z + fy * pb0.z;
  acc[3] = fx * pa0.w + fy * pb0.w;
  acc[4] = fx * pa1.x + fy * pb1.x;
  acc[5] = fx * pa1.y + fy * pb1.y;
  acc[6] = fx * pa1.z + fy * pb1.z;
  acc[7] = fx * pa1.w + fy * pb1.w;
#pragma unroll
  for (int off = 1; off <= 32; off <<= 1) {
#pragma unroll
    for (int k = 0; k < 8; k++) acc[k] += __shfl_xor(acc[k], off);
  }
  if (lane == 0) {
    *(float4*)&a_s[n * 4] = make_float4(acc[0], acc[1], acc[2], acc[3]);
    if (n < N1)
      *(float4*)&a_d[n * 4] = make_float4(acc[4], acc[5], acc[6], acc[7]);
  }
}

// ---------- attn2: a_s2[n]=hid1[n]·p2[:,0], a_d2[n]=hid1[n]·p2[:,1] --------
__global__ __launch_bounds__(256) void attn2_kernel(
    const short* __restrict__ hid1, const float* __restrict__ p2,
    float* __restrict__ a_s, float* __restrict__ a_d) {
  int wid = threadIdx.x >> 6, lane = threadIdx.x & 63;
  long n = (long)blockIdx.x * 4 + wid;
  if (n >= N1) return;
  short4 hv = *(const short4*)&hid1[n * 256 + lane * 4];
  float4 q0 = *(const float4*)&p2[(lane * 4) * 2];      // rows l4,l4+1 (s,d)
  float4 q1 = *(const float4*)&p2[(lane * 4) * 2 + 4];  // rows l4+2,l4+3
  float h0 = bf2f(hv.x), h1 = bf2f(hv.y), h2 = bf2f(hv.z), h3 = bf2f(hv.w);
  float s = h0 * q0.x + h1 * q0.z + h2 * q1.x + h3 * q1.z;
  float d = h0 * q0.y + h1 * q0.w + h2 * q1.y + h3 * q1.w;
#pragma unroll
  for (int off = 1; off <= 32; off <<= 1) {
    s += __shfl_xor(s, off);
    d += __shfl_xor(d, off);
  }
  if (lane == 0) {
    a_s[n] = s;
    if (n < N2) a_d[n] = d;
  }
}

// ---------------- CSR build ----------------
__global__ void hist_kernel(const int* __restrict__ dst, int E,
                            int* __restrict__ deg) {
  int e = blockIdx.x * blockDim.x + threadIdx.x;
  if (e < E) atomicAdd(&deg[dst[e]], 1);
}

__global__ __launch_bounds__(1024) void scan_kernel(
    const int* __restrict__ deg, int n, int* __restrict__ offs,
    int* __restrict__ cursor) {
  __shared__ int part[1024];
  int tid = threadIdx.x;
  int chunk = (n + 1023) / 1024;
  int lo = tid * chunk, hi = min(n, lo + chunk);
  int s = 0;
  for (int i = lo; i < hi; i++) s += deg[i];
  part[tid] = s;
  __syncthreads();
  for (int off = 1; off < 1024; off <<= 1) {
    int v = (tid >= off) ? part[tid - off] : 0;
    __syncthreads();
    part[tid] += v;
    __syncthreads();
  }
  int base = (tid == 0) ? 0 : part[tid - 1];
  for (int i = lo; i < hi; i++) {
    offs[i] = base;
    cursor[i] = base;
    base += deg[i];
  }
  if (tid == 1023) offs[n] = part[1023];
}

// scatter for layer1: writes csr_src and per-edge logits float4 (4 heads)
__global__ void scatter1_kernel(const int* __restrict__ src,
                                const int* __restrict__ dst, int E,
                                int* __restrict__ cursor,
                                const float* __restrict__ a_s,
                                const float* __restrict__ a_d,
                                int* __restrict__ csr_src,
                                float* __restrict__ csr_t) {
  int e = blockIdx.x * blockDim.x + threadIdx.x;
  if (e >= E) return;
  int s = src[e], d = dst[e];
  int p = atomicAdd(&cursor[d], 1);
  csr_src[p] = s;
  float4 as = *(const float4*)&a_s[s * 4];
  float4 ad = *(const float4*)&a_d[d * 4];
  float4 t;
  t.x = lrelu(as.x + ad.x);
  t.y = lrelu(as.y + ad.y);
  t.z = lrelu(as.z + ad.z);
  t.w = lrelu(as.w + ad.w);
  *(float4*)&csr_t[(long)p * 4] = t;
}

// scatter for layer2: scalar logit per edge
__global__ void scatter2_kernel(const int* __restrict__ src,
                                const int* __restrict__ dst, int E,
                                int* __restrict__ cursor,
                                const float* __restrict__ a_s,
                                const float* __restrict__ a_d,
                                int* __restrict__ csr_src,
                                float* __restrict__ csr_t) {
  int e = blockIdx.x * blockDim.x + threadIdx.x;
  if (e >= E) return;
  int s = src[e], d = dst[e];
  int p = atomicAdd(&cursor[d], 1);
  csr_src[p] = s;
  csr_t[p] = lrelu(a_s[s] + a_d[d]);
}

// softmax1: thread per (dst,head) over CSR span -> normalized weights
__global__ void softmax1_kernel(const int* __restrict__ offs,
                                const float* __restrict__ csr_t,
                                float* __restrict__ w) {
  int g = blockIdx.x * blockDim.x + threadIdx.x;
  if (g >= N1 * 4) return;
  int d = g >> 2, h = g & 3;
  int lo = offs[d], deg = offs[d + 1] - lo;
  float m = -INFINITY;
  for (int j = 0; j < deg; j++) m = fmaxf(m, csr_t[(long)(lo + j) * 4 + h]);
  float den = 0.f;
  for (int j = 0; j < deg; j++) {
    float e_ = __expf(csr_t[(long)(lo + j) * 4 + h] - m);
    w[(long)(lo + j) * 4 + h] = e_;
    den += e_;
  }
  float inv = 1.f / (den + 1e-16f);
  for (int j = 0; j < deg; j++) w[(long)(lo + j) * 4 + h] *= inv;
}

__global__ void softmax2_kernel(const int* __restrict__ offs,
                                const float* __restrict__ csr_t,
                                float* __restrict__ w) {
  int d = blockIdx.x * blockDim.x + threadIdx.x;
  if (d >= N2) return;
  int lo = offs[d], deg = offs[d + 1] - lo;
  float m = -INFINITY;
  for (int j = 0; j < deg; j++) m = fmaxf(m, csr_t[lo + j]);
  float den = 0.f;
  for (int j = 0; j < deg; j++) {
    float e_ = __expf(csr_t[lo + j] - m);
    w[lo + j] = e_;
    den += e_;
  }
  float inv = 1.f / (den + 1e-16f);
  for (int j = 0; j < deg; j++) w[lo + j] *= inv;
}

// gather1: z1[d, h*128+c] = sum_e w[e,h] * x[src_e, c]   (wave per node)
__global__ __launch_bounds__(256) void gather1_kernel(
    const short* __restrict__ x, const int* __restrict__ csr_src,
    const float* __restrict__ w, const int* __restrict__ offs,
    short* __restrict__ z1) {
  int wid = threadIdx.x >> 6, lane = threadIdx.x & 63;
  long d = (long)blockIdx.x * 4 + wid;
  if (d >= N1) return;
  int lo = offs[d], deg = offs[d + 1] - lo;
  float acc[4][2] = {};
  for (int j = 0; j < deg; j++) {
    int src = csr_src[lo + j];
    float4 wv = *(const float4*)&w[(long)(lo + j) * 4];
    short2 xv = *(const short2*)&x[(long)src * 128 + lane * 2];
    float fx = bf2f(xv.x), fy = bf2f(xv.y);
    acc[0][0] += wv.x * fx; acc[0][1] += wv.x * fy;
    acc[1][0] += wv.y * fx; acc[1][1] += wv.y * fy;
    acc[2][0] += wv.z * fx; acc[2][1] += wv.z * fy;
    acc[3][0] += wv.w * fx; acc[3][1] += wv.w * fy;
  }
#pragma unroll
  for (int h = 0; h < 4; h++) {
    short2 o;
    o.x = f2bf(acc[h][0]);
    o.y = f2bf(acc[h][1]);
    *(short2*)&z1[d * 512 + h * 128 + lane * 2] = o;
  }
}

// gather2: z2[d, c] = sum_e w[e] * hid1[src_e, c]   (wave per node)
__global__ __launch_bounds__(256) void gather2_kernel(
    const short* __restrict__ hid1, const int* __restrict__ csr_src,
    const float* __restrict__ w, const int* __restrict__ offs,
    short* __restrict__ z2) {
  int wid = threadIdx.x >> 6, lane = threadIdx.x & 63;
  long d = (long)blockIdx.x * 4 + wid;
  if (d >= N2) return;
  int lo = offs[d], deg = offs[d + 1] - lo;
  float acc[4] = {};
  for (int j = 0; j < deg; j++) {
    int src = csr_src[lo + j];
    float wv = w[lo + j];
    short4 hv = *(const short4*)&hid1[(long)src * 256 + lane * 4];
    acc[0] += wv * bf2f(hv.x);
    acc[1] += wv * bf2f(hv.y);
    acc[2] += wv * bf2f(hv.z);
    acc[3] += wv * bf2f(hv.w);
  }
  short4 o;
  o.x = f2bf(acc[0]); o.y = f2bf(acc[1]);
  o.z = f2bf(acc[2]); o.w = f2bf(acc[3]);
  *(short4*)&z2[d * 256 + lane * 4] = o;
}

extern "C" void kernel_launch(void* const* d_in, const int* in_sizes, int n_in,
                              void* d_out, int out_size, void* d_ws,
                              size_t ws_size, hipStream_t stream) {
  const float* x = (const float*)d_in[0];
  const int* es1 = (const int*)d_in[1];
  const int* ed1 = (const int*)d_in[2];
  const int* es2 = (const int*)d_in[3];
  const int* ed2 = (const int*)d_in[4];
  const float* W1 = (const float*)d_in[5];
  const float* att_s1 = (const float*)d_in[6];
  const float* att_d1 = (const float*)d_in[7];
  const float* b1 = (const float*)d_in[8];
  const float* W2 = (const float*)d_in[9];
  const float* att_s2 = (const float*)d_in[10];
  const float* att_d2 = (const float*)d_in[11];
  const float* b2 = (const float*)d_in[12];
  const float* c1w = (const float*)d_in[13];
  const float* c1b = (const float*)d_in[14];
  const float* c2w = (const float*)d_in[15];
  const float* c2b = (const float*)d_in[16];
  float* out = (float*)d_out;

  char* ws = (char*)d_ws;
  size_t off = 0;
  auto alloc = [&](size_t bytes) {
    void* p = ws + off;
    off += (bytes + 255) & ~(size_t)255;
    return p;
  };
  short* x_bf = (short*)alloc((size_t)N0 * 128 * 2);
  short* z1 = (short*)alloc((size_t)N1 * 512 * 2);
  short* hid1 = (short*)alloc((size_t)N1 * 256 * 2);
  short* z2 = (short*)alloc((size_t)N2 * 256 * 2);
  float* p1 = (float*)alloc(128 * 8 * 4);
  short* M1t = (short*)alloc(256 * 512 * 2);
  float* bias1p = (float*)alloc(256 * 4);
  float* p2 = (float*)alloc(256 * 2 * 4);
  short* M2t = (short*)alloc(128 * 256 * 2);
  float* bias2p = (float*)alloc(128 * 4);
  float* as1 = (float*)alloc((size_t)N0 * 4 * 4);
  float* ad1v = (float*)alloc((size_t)N1 * 4 * 4);
  float* as2 = (float*)alloc((size_t)N1 * 4);
  float* ad2v = (float*)alloc((size_t)N2 * 4);
  int* deg1 = (int*)alloc((size_t)N1 * 4);
  int* offs1 = (int*)alloc((size_t)(N1 + 1) * 4);
  int* cur1 = (int*)alloc((size_t)N1 * 4);
  int* csr_src1 = (int*)alloc((size_t)E1 * 4);
  float* csr_t1 = (float*)alloc((size_t)E1 * 4 * 4);
  float* w1 = (float*)alloc((size_t)E1 * 4 * 4);
  int* deg2 = (int*)alloc((size_t)N2 * 4);
  int* offs2 = (int*)alloc((size_t)(N2 + 1) * 4);
  int* cur2 = (int*)alloc((size_t)N2 * 4);
  int* csr_src2 = (int*)alloc((size_t)E2 * 4);
  float* csr_t2 = (float*)alloc((size_t)E2 * 4);
  float* w2 = (float*)alloc((size_t)E2 * 4);

  hipMemsetAsync(deg1, 0, (size_t)N1 * 4, stream);
  hipMemsetAsync(deg2, 0, (size_t)N2 * 4, stream);

  // input cast + weight folding
  f2bf_kernel<<<(N0 * 128 / 4 + 255) / 256, 256, 0, stream>>>(x, x_bf,
                                                              (long)N0 * 128);
  prep_p1_kernel<<<4, 256, 0, stream>>>(W1, att_s1, att_d1, p1);
  prep_M1t_kernel<<<512, 256, 0, stream>>>(W1, c1w, M1t);
  prep_bias1_kernel<<<1, 256, 0, stream>>>(b1, c1w, c1b, bias1p);
  prep_p2_kernel<<<2, 256, 0, stream>>>(W2, att_s2, att_d2, p2);
  prep_M2t_kernel<<<128, 256, 0, stream>>>(W2, c2w, M2t);
  prep_bias2_kernel<<<1, 128, 0, stream>>>(b2, c2w, c2b, bias2p);

  // ---- layer 1 ----
  attn1_kernel<<<(N0 + 3) / 4, 256, 0, stream>>>(x_bf, p1, as1, ad1v);
  hist_kernel<<<(E1 + 255) / 256, 256, 0, stream>>>(ed1, E1, deg1);
  scan_kernel<<<1, 1024, 0, stream>>>(deg1, N1, offs1, cur1);
  scatter1_kernel<<<(E1 + 255) / 256, 256, 0, stream>>>(
      es1, ed1, E1, cur1, as1, ad1v, csr_src1, csr_t1);
  softmax1_kernel<<<(N1 * 4 + 255) / 256, 256, 0, stream>>>(offs1, csr_t1, w1);
  gather1_kernel<<<(N1 + 3) / 4, 256, 0, stream>>>(x_bf, csr_src1, w1, offs1,
                                                   z1);
  // hid1 = z1 @ M1 + bias1'   [N1,256] bf16
  mm_bf16_kernel<true, true><<<dim3(4, (N1 + 127) / 128), 256, 0, stream>>>(
      z1, M1t, bias1p, hid1, N1, 256, 512);

  // ---- layer 2 ----
  attn2_kernel<<<(N1 + 3) / 4, 256, 0, stream>>>(hid1, p2, as2, ad2v);
  hist_kernel<<<(E2 + 255) / 256, 256, 0, stream>>>(ed2, E2, deg2);
  scan_kernel<<<1, 1024, 0, stream>>>(deg2, N2, offs2, cur2);
  scatter2_kernel<<<(E2 + 255) / 256, 256, 0, stream>>>(
      es2, ed2, E2, cur2, as2, ad2v, csr_src2, csr_t2);
  softmax2_kernel<<<(N2 + 255) / 256, 256, 0, stream>>>(offs2, csr_t2, w2);
  gather2_kernel<<<(N2 + 3) / 4, 256, 0, stream>>>(hid1, csr_src2, w2, offs2,
                                                   z2);
  // out = z2 @ M2 + bias2'   [N2,128] f32
  mm_bf16_kernel<true, false><<<dim3(2, (N2 + 127) / 128), 256, 0, stream>>>(
      z2, M2t, bias2p, out, N2, 128, 256);
}

// Round 5
// 333.267 us; speedup vs baseline: 3.0915x; 1.2891x over previous
//
#include <hip/hip_runtime.h>
#include <math.h>

#define IN_DIM 128
#define HID_DIM 256
#define OUT_DIM 128
#define HEADS 4
#define N0 80000
#define N1 40000
#define N2 8000
#define E1 400000
#define E2 128000
#define NEG 0.2f

typedef __attribute__((ext_vector_type(8))) short bf16x8;
typedef __attribute__((ext_vector_type(4))) float f32x4;

__device__ __forceinline__ float bf2f(short s) {
  return __uint_as_float(((unsigned int)(unsigned short)s) << 16);
}
__device__ __forceinline__ short f2bf(float f) {
  unsigned int u = __float_as_uint(f);
  unsigned int r = (u + 0x7FFFu + ((u >> 16) & 1u)) >> 16;
  return (short)r;
}
__device__ __forceinline__ float lrelu(float t) {
  return t > 0.f ? t : NEG * t;
}

// ---------------- elementwise f32 -> bf16 (n multiple of 4) ----------------
__global__ void f2bf_kernel(const float* __restrict__ in, short* __restrict__ out,
                            long n) {
  long idx = ((long)blockIdx.x * blockDim.x + threadIdx.x) * 4;
  if (idx < n) {
    float4 v = *(const float4*)(in + idx);
    short4 o;
    o.x = f2bf(v.x); o.y = f2bf(v.y); o.z = f2bf(v.z); o.w = f2bf(v.w);
    *(short4*)(out + idx) = o;
  }
}

// ------------- prep: p1[i][hh] = sum_c W1[i, h*128+c] * att[h][c] ----------
__global__ void prep_p1_kernel(const float* __restrict__ W1,
                               const float* __restrict__ att_s,
                               const float* __restrict__ att_d,
                               float* __restrict__ p1) {
  int g = blockIdx.x * blockDim.x + threadIdx.x;
  if (g >= 128 * 8) return;
  int i = g >> 3, hh = g & 7;
  int h = hh & 3;
  const float* att = (hh < 4) ? att_s : att_d;
  float acc = 0.f;
  for (int c = 0; c < 128; c++)
    acc += W1[(long)i * 512 + h * 128 + c] * att[h * 128 + c];
  p1[g] = acc;
}

// --- prep: M1t[o][kf] = sum_c W1[k, h*128+c] * c1w[o, h*128+c], kf=h*128+k --
__global__ void prep_M1t_kernel(const float* __restrict__ W1,
                                const float* __restrict__ c1w,
                                short* __restrict__ M1t) {
  int g = blockIdx.x * blockDim.x + threadIdx.x;
  if (g >= 256 * 512) return;
  int o = g >> 9, kf = g & 511;
  int h = kf >> 7, k = kf & 127;
  float acc = 0.f;
  for (int c = 0; c < 128; c++)
    acc += W1[(long)k * 512 + h * 128 + c] * c1w[(long)o * 512 + h * 128 + c];
  M1t[g] = f2bf(acc);
}

__global__ void prep_bias1_kernel(const float* __restrict__ b1,
                                  const float* __restrict__ c1w,
                                  const float* __restrict__ c1b,
                                  float* __restrict__ bias1p) {
  int o = blockIdx.x * blockDim.x + threadIdx.x;
  if (o >= 256) return;
  float acc = c1b[o];
  for (int c = 0; c < 512; c++) acc += b1[c] * c1w[(long)o * 512 + c];
  bias1p[o] = acc;
}

__global__ void prep_p2_kernel(const float* __restrict__ W2,
                               const float* __restrict__ att_s,
                               const float* __restrict__ att_d,
                               float* __restrict__ p2) {
  int g = blockIdx.x * blockDim.x + threadIdx.x;
  if (g >= 512) return;
  int k = g >> 1, j = g & 1;
  const float* att = j ? att_d : att_s;
  float acc = 0.f;
  for (int c = 0; c < 256; c++) acc += W2[(long)k * 256 + c] * att[c];
  p2[g] = acc;
}

__global__ void prep_M2t_kernel(const float* __restrict__ W2,
                                const float* __restrict__ c2w,
                                short* __restrict__ M2t) {
  int g = blockIdx.x * blockDim.x + threadIdx.x;
  if (g >= 128 * 256) return;
  int o = g >> 8, k = g & 255;
  float acc = 0.f;
  for (int c = 0; c < 256; c++)
    acc += W2[(long)k * 256 + c] * c2w[(long)o * 256 + c];
  M2t[g] = f2bf(acc);
}

__global__ void prep_bias2_kernel(const float* __restrict__ b2,
                                  const float* __restrict__ c2w,
                                  const float* __restrict__ c2b,
                                  float* __restrict__ bias2p) {
  int o = blockIdx.x * blockDim.x + threadIdx.x;
  if (o >= 128) return;
  float acc = c2b[o];
  for (int c = 0; c < 256; c++) acc += b2[c] * c2w[(long)o * 256 + c];
  bias2p[o] = acc;
}

// ---------------- bf16 MFMA GEMM: C[M,N] = A[M,K] @ Bt[N,K]^T (+bias) -----
template<bool BIAS, bool OUTBF>
__global__ __launch_bounds__(256) void mm_bf16_kernel(
    const short* __restrict__ A, const short* __restrict__ Bt,
    const float* __restrict__ bias, void* __restrict__ Cv,
    int M, int N, int K) {
  __shared__ short As[128][40];
  __shared__ short Bs[64][40];
  int tid = threadIdx.x;
  int bn = blockIdx.x * 64;
  int bm = blockIdx.y * 128;
  int w = tid >> 6;
  int lane = tid & 63;
  int lr = lane & 15, kb = lane >> 4;
  f32x4 acc[2][4] = {};

  for (int k0 = 0; k0 < K; k0 += 32) {
#pragma unroll
    for (int i = 0; i < 2; i++) {
      int seg = tid + i * 256;
      int row = seg >> 2, part = seg & 3;
      int gm = bm + row;
      bf16x8 v = {0, 0, 0, 0, 0, 0, 0, 0};
      if (gm < M) v = *(const bf16x8*)(A + (long)gm * K + k0 + part * 8);
      *(bf16x8*)&As[row][part * 8] = v;
    }
    {
      int r = tid >> 2, part = tid & 3;
      *(bf16x8*)&Bs[r][part * 8] =
          *(const bf16x8*)(Bt + (long)(bn + r) * K + k0 + part * 8);
    }
    __syncthreads();
    bf16x8 a0 = *(const bf16x8*)&As[w * 32 + lr][kb * 8];
    bf16x8 a1 = *(const bf16x8*)&As[w * 32 + 16 + lr][kb * 8];
    bf16x8 b0 = *(const bf16x8*)&Bs[lr][kb * 8];
    bf16x8 b1 = *(const bf16x8*)&Bs[16 + lr][kb * 8];
    bf16x8 b2 = *(const bf16x8*)&Bs[32 + lr][kb * 8];
    bf16x8 b3 = *(const bf16x8*)&Bs[48 + lr][kb * 8];
    acc[0][0] = __builtin_amdgcn_mfma_f32_16x16x32_bf16(a0, b0, acc[0][0], 0, 0, 0);
    acc[0][1] = __builtin_amdgcn_mfma_f32_16x16x32_bf16(a0, b1, acc[0][1], 0, 0, 0);
    acc[0][2] = __builtin_amdgcn_mfma_f32_16x16x32_bf16(a0, b2, acc[0][2], 0, 0, 0);
    acc[0][3] = __builtin_amdgcn_mfma_f32_16x16x32_bf16(a0, b3, acc[0][3], 0, 0, 0);
    acc[1][0] = __builtin_amdgcn_mfma_f32_16x16x32_bf16(a1, b0, acc[1][0], 0, 0, 0);
    acc[1][1] = __builtin_amdgcn_mfma_f32_16x16x32_bf16(a1, b1, acc[1][1], 0, 0, 0);
    acc[1][2] = __builtin_amdgcn_mfma_f32_16x16x32_bf16(a1, b2, acc[1][2], 0, 0, 0);
    acc[1][3] = __builtin_amdgcn_mfma_f32_16x16x32_bf16(a1, b3, acc[1][3], 0, 0, 0);
    __syncthreads();
  }
#pragma unroll
  for (int mt = 0; mt < 2; mt++) {
#pragma unroll
    for (int nt = 0; nt < 4; nt++) {
#pragma unroll
      for (int r = 0; r < 4; r++) {
        int row = bm + w * 32 + mt * 16 + kb * 4 + r;
        if (row >= M) continue;
        int col = bn + nt * 16 + lr;
        float v = acc[mt][nt][r];
        if (BIAS) v += bias[col];
        if (OUTBF)
          ((short*)Cv)[(long)row * N + col] = f2bf(v);
        else
          ((float*)Cv)[(long)row * N + col] = v;
      }
    }
  }
}

// ---------- attn1 ----------
__global__ __launch_bounds__(256) void attn1_kernel(
    const short* __restrict__ x, const float* __restrict__ p1,
    float* __restrict__ a_s, float* __restrict__ a_d) {
  int wid = threadIdx.x >> 6, lane = threadIdx.x & 63;
  long n = (long)blockIdx.x * 4 + wid;
  if (n >= N0) return;
  short2 xv = *(const short2*)&x[n * 128 + lane * 2];
  float fx = bf2f(xv.x), fy = bf2f(xv.y);
  float4 pa0 = *(const float4*)&p1[(lane * 2) * 8];
  float4 pa1 = *(const float4*)&p1[(lane * 2) * 8 + 4];
  float4 pb0 = *(const float4*)&p1[(lane * 2 + 1) * 8];
  float4 pb1 = *(const float4*)&p1[(lane * 2 + 1) * 8 + 4];
  float acc[8];
  acc[0] = fx * pa0.x + fy * pb0.x;
  acc[1] = fx * pa0.y + fy * pb0.y;
  acc[2] = fx * pa0.z + fy * pb0.z;
  acc[3] = fx * pa0.w + fy * pb0.w;
  acc[4] = fx * pa1.x + fy * pb1.x;
  acc[5] = fx * pa1.y + fy * pb1.y;
  acc[6] = fx * pa1.z + fy * pb1.z;
  acc[7] = fx * pa1.w + fy * pb1.w;
#pragma unroll
  for (int off = 1; off <= 32; off <<= 1) {
#pragma unroll
    for (int k = 0; k < 8; k++) acc[k] += __shfl_xor(acc[k], off);
  }
  if (lane == 0) {
    *(float4*)&a_s[n * 4] = make_float4(acc[0], acc[1], acc[2], acc[3]);
    if (n < N1)
      *(float4*)&a_d[n * 4] = make_float4(acc[4], acc[5], acc[6], acc[7]);
  }
}

// ---------- attn2 ----------
__global__ __launch_bounds__(256) void attn2_kernel(
    const short* __restrict__ hid1, const float* __restrict__ p2,
    float* __restrict__ a_s, float* __restrict__ a_d) {
  int wid = threadIdx.x >> 6, lane = threadIdx.x & 63;
  long n = (long)blockIdx.x * 4 + wid;
  if (n >= N1) return;
  short4 hv = *(const short4*)&hid1[n * 256 + lane * 4];
  float4 q0 = *(const float4*)&p2[(lane * 4) * 2];
  float4 q1 = *(const float4*)&p2[(lane * 4) * 2 + 4];
  float h0 = bf2f(hv.x), h1 = bf2f(hv.y), h2 = bf2f(hv.z), h3 = bf2f(hv.w);
  float s = h0 * q0.x + h1 * q0.z + h2 * q1.x + h3 * q1.z;
  float d = h0 * q0.y + h1 * q0.w + h2 * q1.y + h3 * q1.w;
#pragma unroll
  for (int off = 1; off <= 32; off <<= 1) {
    s += __shfl_xor(s, off);
    d += __shfl_xor(d, off);
  }
  if (lane == 0) {
    a_s[n] = s;
    if (n < N2) a_d[n] = d;
  }
}

// ---------------- CSR build: hist (+rank) ----------------
__global__ void hist_kernel(const int* __restrict__ dst, int E,
                            int* __restrict__ deg, int* __restrict__ rank) {
  int e = blockIdx.x * blockDim.x + threadIdx.x;
  if (e < E) rank[e] = atomicAdd(&deg[dst[e]], 1);
}

// ---------------- hierarchical exclusive scan (3 kernels) ----------------
// A: per-block (tile=1024) sums
__global__ __launch_bounds__(256) void scanA_kernel(const int* __restrict__ deg,
                                                    int n,
                                                    int* __restrict__ part) {
  __shared__ int red[256];
  int base = blockIdx.x * 1024;
  int s = 0;
  for (int i = threadIdx.x; i < 1024; i += 256) {
    int idx = base + i;
    if (idx < n) s += deg[idx];
  }
  red[threadIdx.x] = s;
  __syncthreads();
  for (int off = 128; off >= 1; off >>= 1) {
    if (threadIdx.x < off) red[threadIdx.x] += red[threadIdx.x + off];
    __syncthreads();
  }
  if (threadIdx.x == 0) part[blockIdx.x] = red[0];
}

// B: single-wave exclusive scan of partials (nb <= 64)
__global__ __launch_bounds__(64) void scanB_kernel(int* __restrict__ part,
                                                   int nb) {
  int tid = threadIdx.x;
  int orig = (tid < nb) ? part[tid] : 0;
  int v = orig;
#pragma unroll
  for (int off = 1; off < 64; off <<= 1) {
    int t = __shfl_up(v, off);
    if (tid >= off) v += t;
  }
  if (tid < nb) part[tid] = v - orig;
}

// C: per-block local exclusive scan + block offset -> offs[0..n]
__global__ __launch_bounds__(256) void scanC_kernel(const int* __restrict__ deg,
                                                    int n,
                                                    const int* __restrict__ part,
                                                    int* __restrict__ offs) {
  __shared__ int tsum[256];
  int base = blockIdx.x * 1024;
  int v[4];
  int s = 0;
#pragma unroll
  for (int k = 0; k < 4; k++) {
    int idx = base + threadIdx.x * 4 + k;
    v[k] = (idx < n) ? deg[idx] : 0;
    s += v[k];
  }
  tsum[threadIdx.x] = s;
  __syncthreads();
  for (int off = 1; off < 256; off <<= 1) {
    int t = (threadIdx.x >= off) ? tsum[threadIdx.x - off] : 0;
    __syncthreads();
    tsum[threadIdx.x] += t;
    __syncthreads();
  }
  int run = part[blockIdx.x] + ((threadIdx.x > 0) ? tsum[threadIdx.x - 1] : 0);
#pragma unroll
  for (int k = 0; k < 4; k++) {
    int idx = base + threadIdx.x * 4 + k;
    if (idx < n) {
      offs[idx] = run;
      run += v[k];
    }
  }
  if (blockIdx.x == gridDim.x - 1 && threadIdx.x == 255)
    offs[n] = part[blockIdx.x] + tsum[255];
}

// scatter layer1 (no atomics: pos = offs[d] + rank[e])
__global__ void scatter1_kernel(const int* __restrict__ src,
                                const int* __restrict__ dst, int E,
                                const int* __restrict__ offs,
                                const int* __restrict__ rank,
                                const float* __restrict__ a_s,
                                const float* __restrict__ a_d,
                                int* __restrict__ csr_src,
                                float* __restrict__ csr_t) {
  int e = blockIdx.x * blockDim.x + threadIdx.x;
  if (e >= E) return;
  int s = src[e], d = dst[e];
  int p = offs[d] + rank[e];
  csr_src[p] = s;
  float4 as = *(const float4*)&a_s[s * 4];
  float4 ad = *(const float4*)&a_d[d * 4];
  float4 t;
  t.x = lrelu(as.x + ad.x);
  t.y = lrelu(as.y + ad.y);
  t.z = lrelu(as.z + ad.z);
  t.w = lrelu(as.w + ad.w);
  *(float4*)&csr_t[(long)p * 4] = t;
}

__global__ void scatter2_kernel(const int* __restrict__ src,
                                const int* __restrict__ dst, int E,
                                const int* __restrict__ offs,
                                const int* __restrict__ rank,
                                const float* __restrict__ a_s,
                                const float* __restrict__ a_d,
                                int* __restrict__ csr_src,
                                float* __restrict__ csr_t) {
  int e = blockIdx.x * blockDim.x + threadIdx.x;
  if (e >= E) return;
  int s = src[e], d = dst[e];
  int p = offs[d] + rank[e];
  csr_src[p] = s;
  csr_t[p] = lrelu(a_s[s] + a_d[d]);
}

// softmax1: thread per (dst,head)
__global__ void softmax1_kernel(const int* __restrict__ offs,
                                const float* __restrict__ csr_t,
                                float* __restrict__ w) {
  int g = blockIdx.x * blockDim.x + threadIdx.x;
  if (g >= N1 * 4) return;
  int d = g >> 2, h = g & 3;
  int lo = offs[d], deg = offs[d + 1] - lo;
  float m = -INFINITY;
  for (int j = 0; j < deg; j++) m = fmaxf(m, csr_t[(long)(lo + j) * 4 + h]);
  float den = 0.f;
  for (int j = 0; j < deg; j++) {
    float e_ = __expf(csr_t[(long)(lo + j) * 4 + h] - m);
    w[(long)(lo + j) * 4 + h] = e_;
    den += e_;
  }
  float inv = 1.f / (den + 1e-16f);
  for (int j = 0; j < deg; j++) w[(long)(lo + j) * 4 + h] *= inv;
}

__global__ void softmax2_kernel(const int* __restrict__ offs,
                                const float* __restrict__ csr_t,
                                float* __restrict__ w) {
  int d = blockIdx.x * blockDim.x + threadIdx.x;
  if (d >= N2) return;
  int lo = offs[d], deg = offs[d + 1] - lo;
  float m = -INFINITY;
  for (int j = 0; j < deg; j++) m = fmaxf(m, csr_t[lo + j]);
  float den = 0.f;
  for (int j = 0; j < deg; j++) {
    float e_ = __expf(csr_t[lo + j] - m);
    w[lo + j] = e_;
    den += e_;
  }
  float inv = 1.f / (den + 1e-16f);
  for (int j = 0; j < deg; j++) w[lo + j] *= inv;
}

// gather1: z1[d, h*128+c] = sum_e w[e,h] * x[src_e, c]   (wave per node)
__global__ __launch_bounds__(256) void gather1_kernel(
    const short* __restrict__ x, const int* __restrict__ csr_src,
    const float* __restrict__ w, const int* __restrict__ offs,
    short* __restrict__ z1) {
  int wid = threadIdx.x >> 6, lane = threadIdx.x & 63;
  long d = (long)blockIdx.x * 4 + wid;
  if (d >= N1) return;
  int lo = offs[d], deg = offs[d + 1] - lo;
  float acc[4][2] = {};
  for (int j = 0; j < deg; j++) {
    int src = csr_src[lo + j];
    float4 wv = *(const float4*)&w[(long)(lo + j) * 4];
    short2 xv = *(const short2*)&x[(long)src * 128 + lane * 2];
    float fx = bf2f(xv.x), fy = bf2f(xv.y);
    acc[0][0] += wv.x * fx; acc[0][1] += wv.x * fy;
    acc[1][0] += wv.y * fx; acc[1][1] += wv.y * fy;
    acc[2][0] += wv.z * fx; acc[2][1] += wv.z * fy;
    acc[3][0] += wv.w * fx; acc[3][1] += wv.w * fy;
  }
#pragma unroll
  for (int h = 0; h < 4; h++) {
    short2 o;
    o.x = f2bf(acc[h][0]);
    o.y = f2bf(acc[h][1]);
    *(short2*)&z1[d * 512 + h * 128 + lane * 2] = o;
  }
}

// gather2: z2[d, c] = sum_e w[e] * hid1[src_e, c]   (wave per node)
__global__ __launch_bounds__(256) void gather2_kernel(
    const short* __restrict__ hid1, const int* __restrict__ csr_src,
    const float* __restrict__ w, const int* __restrict__ offs,
    short* __restrict__ z2) {
  int wid = threadIdx.x >> 6, lane = threadIdx.x & 63;
  long d = (long)blockIdx.x * 4 + wid;
  if (d >= N2) return;
  int lo = offs[d], deg = offs[d + 1] - lo;
  float acc[4] = {};
  for (int j = 0; j < deg; j++) {
    int src = csr_src[lo + j];
    float wv = w[lo + j];
    short4 hv = *(const short4*)&hid1[(long)src * 256 + lane * 4];
    acc[0] += wv * bf2f(hv.x);
    acc[1] += wv * bf2f(hv.y);
    acc[2] += wv * bf2f(hv.z);
    acc[3] += wv * bf2f(hv.w);
  }
  short4 o;
  o.x = f2bf(acc[0]); o.y = f2bf(acc[1]);
  o.z = f2bf(acc[2]); o.w = f2bf(acc[3]);
  *(short4*)&z2[d * 256 + lane * 4] = o;
}

extern "C" void kernel_launch(void* const* d_in, const int* in_sizes, int n_in,
                              void* d_out, int out_size, void* d_ws,
                              size_t ws_size, hipStream_t stream) {
  const float* x = (const float*)d_in[0];
  const int* es1 = (const int*)d_in[1];
  const int* ed1 = (const int*)d_in[2];
  const int* es2 = (const int*)d_in[3];
  const int* ed2 = (const int*)d_in[4];
  const float* W1 = (const float*)d_in[5];
  const float* att_s1 = (const float*)d_in[6];
  const float* att_d1 = (const float*)d_in[7];
  const float* b1 = (const float*)d_in[8];
  const float* W2 = (const float*)d_in[9];
  const float* att_s2 = (const float*)d_in[10];
  const float* att_d2 = (const float*)d_in[11];
  const float* b2 = (const float*)d_in[12];
  const float* c1w = (const float*)d_in[13];
  const float* c1b = (const float*)d_in[14];
  const float* c2w = (const float*)d_in[15];
  const float* c2b = (const float*)d_in[16];
  float* out = (float*)d_out;

  char* ws = (char*)d_ws;
  size_t off = 0;
  auto alloc = [&](size_t bytes) {
    void* p = ws + off;
    off += (bytes + 255) & ~(size_t)255;
    return p;
  };
  short* x_bf = (short*)alloc((size_t)N0 * 128 * 2);
  short* z1 = (short*)alloc((size_t)N1 * 512 * 2);
  short* hid1 = (short*)alloc((size_t)N1 * 256 * 2);
  short* z2 = (short*)alloc((size_t)N2 * 256 * 2);
  float* p1 = (float*)alloc(128 * 8 * 4);
  short* M1t = (short*)alloc(256 * 512 * 2);
  float* bias1p = (float*)alloc(256 * 4);
  float* p2 = (float*)alloc(256 * 2 * 4);
  short* M2t = (short*)alloc(128 * 256 * 2);
  float* bias2p = (float*)alloc(128 * 4);
  float* as1 = (float*)alloc((size_t)N0 * 4 * 4);
  float* ad1v = (float*)alloc((size_t)N1 * 4 * 4);
  float* as2 = (float*)alloc((size_t)N1 * 4);
  float* ad2v = (float*)alloc((size_t)N2 * 4);
  int* deg1 = (int*)alloc((size_t)N1 * 4);
  int* offs1 = (int*)alloc((size_t)(N1 + 1) * 4);
  int* rank1 = (int*)alloc((size_t)E1 * 4);
  int* part1 = (int*)alloc(64 * 4);
  int* csr_src1 = (int*)alloc((size_t)E1 * 4);
  float* csr_t1 = (float*)alloc((size_t)E1 * 4 * 4);
  float* w1 = (float*)alloc((size_t)E1 * 4 * 4);
  int* deg2 = (int*)alloc((size_t)N2 * 4);
  int* offs2 = (int*)alloc((size_t)(N2 + 1) * 4);
  int* rank2 = (int*)alloc((size_t)E2 * 4);
  int* part2 = (int*)alloc(64 * 4);
  int* csr_src2 = (int*)alloc((size_t)E2 * 4);
  float* csr_t2 = (float*)alloc((size_t)E2 * 4);
  float* w2 = (float*)alloc((size_t)E2 * 4);

  const int NB1 = (N1 + 1023) / 1024;  // 40
  const int NB2 = (N2 + 1023) / 1024;  // 8

  hipMemsetAsync(deg1, 0, (size_t)N1 * 4, stream);
  hipMemsetAsync(deg2, 0, (size_t)N2 * 4, stream);

  // input cast + weight folding
  f2bf_kernel<<<(N0 * 128 / 4 + 255) / 256, 256, 0, stream>>>(x, x_bf,
                                                              (long)N0 * 128);
  prep_p1_kernel<<<4, 256, 0, stream>>>(W1, att_s1, att_d1, p1);
  prep_M1t_kernel<<<512, 256, 0, stream>>>(W1, c1w, M1t);
  prep_bias1_kernel<<<1, 256, 0, stream>>>(b1, c1w, c1b, bias1p);
  prep_p2_kernel<<<2, 256, 0, stream>>>(W2, att_s2, att_d2, p2);
  prep_M2t_kernel<<<128, 256, 0, stream>>>(W2, c2w, M2t);
  prep_bias2_kernel<<<1, 128, 0, stream>>>(b2, c2w, c2b, bias2p);

  // ---- layer 1 ----
  attn1_kernel<<<(N0 + 3) / 4, 256, 0, stream>>>(x_bf, p1, as1, ad1v);
  hist_kernel<<<(E1 + 255) / 256, 256, 0, stream>>>(ed1, E1, deg1, rank1);
  scanA_kernel<<<NB1, 256, 0, stream>>>(deg1, N1, part1);
  scanB_kernel<<<1, 64, 0, stream>>>(part1, NB1);
  scanC_kernel<<<NB1, 256, 0, stream>>>(deg1, N1, part1, offs1);
  scatter1_kernel<<<(E1 + 255) / 256, 256, 0, stream>>>(
      es1, ed1, E1, offs1, rank1, as1, ad1v, csr_src1, csr_t1);
  softmax1_kernel<<<(N1 * 4 + 255) / 256, 256, 0, stream>>>(offs1, csr_t1, w1);
  gather1_kernel<<<(N1 + 3) / 4, 256, 0, stream>>>(x_bf, csr_src1, w1, offs1,
                                                   z1);
  // hid1 = z1 @ M1 + bias1'
  mm_bf16_kernel<true, true><<<dim3(4, (N1 + 127) / 128), 256, 0, stream>>>(
      z1, M1t, bias1p, hid1, N1, 256, 512);

  // ---- layer 2 ----
  attn2_kernel<<<(N1 + 3) / 4, 256, 0, stream>>>(hid1, p2, as2, ad2v);
  hist_kernel<<<(E2 + 255) / 256, 256, 0, stream>>>(ed2, E2, deg2, rank2);
  scanA_kernel<<<NB2, 256, 0, stream>>>(deg2, N2, part2);
  scanB_kernel<<<1, 64, 0, stream>>>(part2, NB2);
  scanC_kernel<<<NB2, 256, 0, stream>>>(deg2, N2, part2, offs2);
  scatter2_kernel<<<(E2 + 255) / 256, 256, 0, stream>>>(
      es2, ed2, E2, offs2, rank2, as2, ad2v, csr_src2, csr_t2);
  softmax2_kernel<<<(N2 + 255) / 256, 256, 0, stream>>>(offs2, csr_t2, w2);
  gather2_kernel<<<(N2 + 3) / 4, 256, 0, stream>>>(hid1, csr_src2, w2, offs2,
                                                   z2);
  // out = z2 @ M2 + bias2'
  mm_bf16_kernel<true, false><<<dim3(2, (N2 + 127) / 128), 256, 0, stream>>>(
      z2, M2t, bias2p, out, N2, 128, 256);
}

// Round 6
// 238.787 us; speedup vs baseline: 4.3147x; 1.3957x over previous
//
#include <hip/hip_runtime.h>
#include <math.h>

#define IN_DIM 128
#define HID_DIM 256
#define OUT_DIM 128
#define HEADS 4
#define N0 80000
#define N1 40000
#define N2 8000
#define E1 400000
#define E2 128000
#define NEG 0.2f
#define NB1 40
#define NB2 8

typedef __attribute__((ext_vector_type(8))) short bf16x8;
typedef __attribute__((ext_vector_type(4))) float f32x4;

__device__ __forceinline__ float bf2f(short s) {
  return __uint_as_float(((unsigned int)(unsigned short)s) << 16);
}
__device__ __forceinline__ short f2bf(float f) {
  unsigned int u = __float_as_uint(f);
  unsigned int r = (u + 0x7FFFu + ((u >> 16) & 1u)) >> 16;
  return (short)r;
}
__device__ __forceinline__ float lrelu(float t) {
  return t > 0.f ? t : NEG * t;
}

// ---------------- fused prep: all weight folding in one dispatch ----------
// blocks [0,512): M1t ; [512,640): M2t ; [640,644): p1 ; 644: bias1p ;
// [645,647): p2 ; 647: bias2p
__global__ __launch_bounds__(256) void prep_all_kernel(
    const float* __restrict__ W1, const float* __restrict__ att_s1,
    const float* __restrict__ att_d1, const float* __restrict__ b1,
    const float* __restrict__ c1w, const float* __restrict__ c1b,
    const float* __restrict__ W2, const float* __restrict__ att_s2,
    const float* __restrict__ att_d2, const float* __restrict__ b2,
    const float* __restrict__ c2w, const float* __restrict__ c2b,
    short* __restrict__ M1t, float* __restrict__ p1,
    float* __restrict__ bias1p, short* __restrict__ M2t,
    float* __restrict__ p2, float* __restrict__ bias2p) {
  int b = blockIdx.x, t = threadIdx.x;
  if (b < 512) {  // M1t[o][kf] = sum_c W1[k, h*128+c]*c1w[o, h*128+c]
    int g = b * 256 + t;
    int o = g >> 9, kf = g & 511;
    int h = kf >> 7, k = kf & 127;
    float acc = 0.f;
    for (int c = 0; c < 128; c++)
      acc += W1[(long)k * 512 + h * 128 + c] * c1w[(long)o * 512 + h * 128 + c];
    M1t[g] = f2bf(acc);
  } else if (b < 640) {  // M2t[o][k] = sum_c W2[k,c]*c2w[o,c]
    int g = (b - 512) * 256 + t;
    int o = g >> 8, k = g & 255;
    float acc = 0.f;
    for (int c = 0; c < 256; c++)
      acc += W2[(long)k * 256 + c] * c2w[(long)o * 256 + c];
    M2t[g] = f2bf(acc);
  } else if (b < 644) {  // p1[i][hh]
    int g = (b - 640) * 256 + t;
    int i = g >> 3, hh = g & 7;
    int h = hh & 3;
    const float* att = (hh < 4) ? att_s1 : att_d1;
    float acc = 0.f;
    for (int c = 0; c < 128; c++)
      acc += W1[(long)i * 512 + h * 128 + c] * att[h * 128 + c];
    p1[g] = acc;
  } else if (b == 644) {  // bias1p
    if (t < 256) {
      float acc = c1b[t];
      for (int c = 0; c < 512; c++) acc += b1[c] * c1w[(long)t * 512 + c];
      bias1p[t] = acc;
    }
  } else if (b < 647) {  // p2[k][j]
    int g = (b - 645) * 256 + t;
    if (g < 512) {
      int k = g >> 1, j = g & 1;
      const float* att = j ? att_d2 : att_s2;
      float acc = 0.f;
      for (int c = 0; c < 256; c++) acc += W2[(long)k * 256 + c] * att[c];
      p2[g] = acc;
    }
  } else {  // bias2p
    if (t < 128) {
      float acc = c2b[t];
      for (int c = 0; c < 256; c++) acc += b2[c] * c2w[(long)t * 256 + c];
      bias2p[t] = acc;
    }
  }
}

// ---------------- bf16 MFMA GEMM: C[M,N] = A[M,K] @ Bt[N,K]^T (+bias) -----
template<bool BIAS, bool OUTBF>
__global__ __launch_bounds__(256) void mm_bf16_kernel(
    const short* __restrict__ A, const short* __restrict__ Bt,
    const float* __restrict__ bias, void* __restrict__ Cv,
    int M, int N, int K) {
  __shared__ short As[128][40];
  __shared__ short Bs[64][40];
  int tid = threadIdx.x;
  int bn = blockIdx.x * 64;
  int bm = blockIdx.y * 128;
  int w = tid >> 6;
  int lane = tid & 63;
  int lr = lane & 15, kb = lane >> 4;
  f32x4 acc[2][4] = {};

  for (int k0 = 0; k0 < K; k0 += 32) {
#pragma unroll
    for (int i = 0; i < 2; i++) {
      int seg = tid + i * 256;
      int row = seg >> 2, part = seg & 3;
      int gm = bm + row;
      bf16x8 v = {0, 0, 0, 0, 0, 0, 0, 0};
      if (gm < M) v = *(const bf16x8*)(A + (long)gm * K + k0 + part * 8);
      *(bf16x8*)&As[row][part * 8] = v;
    }
    {
      int r = tid >> 2, part = tid & 3;
      *(bf16x8*)&Bs[r][part * 8] =
          *(const bf16x8*)(Bt + (long)(bn + r) * K + k0 + part * 8);
    }
    __syncthreads();
    bf16x8 a0 = *(const bf16x8*)&As[w * 32 + lr][kb * 8];
    bf16x8 a1 = *(const bf16x8*)&As[w * 32 + 16 + lr][kb * 8];
    bf16x8 b0 = *(const bf16x8*)&Bs[lr][kb * 8];
    bf16x8 b1 = *(const bf16x8*)&Bs[16 + lr][kb * 8];
    bf16x8 b2 = *(const bf16x8*)&Bs[32 + lr][kb * 8];
    bf16x8 b3 = *(const bf16x8*)&Bs[48 + lr][kb * 8];
    acc[0][0] = __builtin_amdgcn_mfma_f32_16x16x32_bf16(a0, b0, acc[0][0], 0, 0, 0);
    acc[0][1] = __builtin_amdgcn_mfma_f32_16x16x32_bf16(a0, b1, acc[0][1], 0, 0, 0);
    acc[0][2] = __builtin_amdgcn_mfma_f32_16x16x32_bf16(a0, b2, acc[0][2], 0, 0, 0);
    acc[0][3] = __builtin_amdgcn_mfma_f32_16x16x32_bf16(a0, b3, acc[0][3], 0, 0, 0);
    acc[1][0] = __builtin_amdgcn_mfma_f32_16x16x32_bf16(a1, b0, acc[1][0], 0, 0, 0);
    acc[1][1] = __builtin_amdgcn_mfma_f32_16x16x32_bf16(a1, b1, acc[1][1], 0, 0, 0);
    acc[1][2] = __builtin_amdgcn_mfma_f32_16x16x32_bf16(a1, b2, acc[1][2], 0, 0, 0);
    acc[1][3] = __builtin_amdgcn_mfma_f32_16x16x32_bf16(a1, b3, acc[1][3], 0, 0, 0);
    __syncthreads();
  }
#pragma unroll
  for (int mt = 0; mt < 2; mt++) {
#pragma unroll
    for (int nt = 0; nt < 4; nt++) {
#pragma unroll
      for (int r = 0; r < 4; r++) {
        int row = bm + w * 32 + mt * 16 + kb * 4 + r;
        if (row >= M) continue;
        int col = bn + nt * 16 + lr;
        float v = acc[mt][nt][r];
        if (BIAS) v += bias[col];
        if (OUTBF)
          ((short*)Cv)[(long)row * N + col] = f2bf(v);
        else
          ((float*)Cv)[(long)row * N + col] = v;
      }
    }
  }
}

// ---------- fused cast + attn1: read x f32, write x_bf, attn dots ----------
__global__ __launch_bounds__(256) void cast_attn1_kernel(
    const float* __restrict__ x, const float* __restrict__ p1,
    short* __restrict__ x_bf, float* __restrict__ a_s,
    float* __restrict__ a_d) {
  int wid = threadIdx.x >> 6, lane = threadIdx.x & 63;
  long n = (long)blockIdx.x * 4 + wid;
  if (n >= N0) return;
  float2 xv = *(const float2*)&x[n * 128 + lane * 2];
  short2 o;
  o.x = f2bf(xv.x);
  o.y = f2bf(xv.y);
  *(short2*)&x_bf[n * 128 + lane * 2] = o;
  float fx = xv.x, fy = xv.y;
  float4 pa0 = *(const float4*)&p1[(lane * 2) * 8];
  float4 pa1 = *(const float4*)&p1[(lane * 2) * 8 + 4];
  float4 pb0 = *(const float4*)&p1[(lane * 2 + 1) * 8];
  float4 pb1 = *(const float4*)&p1[(lane * 2 + 1) * 8 + 4];
  float acc[8];
  acc[0] = fx * pa0.x + fy * pb0.x;
  acc[1] = fx * pa0.y + fy * pb0.y;
  acc[2] = fx * pa0.z + fy * pb0.z;
  acc[3] = fx * pa0.w + fy * pb0.w;
  acc[4] = fx * pa1.x + fy * pb1.x;
  acc[5] = fx * pa1.y + fy * pb1.y;
  acc[6] = fx * pa1.z + fy * pb1.z;
  acc[7] = fx * pa1.w + fy * pb1.w;
#pragma unroll
  for (int off = 1; off <= 32; off <<= 1) {
#pragma unroll
    for (int k = 0; k < 8; k++) acc[k] += __shfl_xor(acc[k], off);
  }
  if (lane == 0) {
    *(float4*)&a_s[n * 4] = make_float4(acc[0], acc[1], acc[2], acc[3]);
    if (n < N1)
      *(float4*)&a_d[n * 4] = make_float4(acc[4], acc[5], acc[6], acc[7]);
  }
}

// ---------- attn2 ----------
__global__ __launch_bounds__(256) void attn2_kernel(
    const short* __restrict__ hid1, const float* __restrict__ p2,
    float* __restrict__ a_s, float* __restrict__ a_d) {
  int wid = threadIdx.x >> 6, lane = threadIdx.x & 63;
  long n = (long)blockIdx.x * 4 + wid;
  if (n >= N1) return;
  short4 hv = *(const short4*)&hid1[n * 256 + lane * 4];
  float4 q0 = *(const float4*)&p2[(lane * 4) * 2];
  float4 q1 = *(const float4*)&p2[(lane * 4) * 2 + 4];
  float h0 = bf2f(hv.x), h1 = bf2f(hv.y), h2 = bf2f(hv.z), h3 = bf2f(hv.w);
  float s = h0 * q0.x + h1 * q0.z + h2 * q1.x + h3 * q1.z;
  float d = h0 * q0.y + h1 * q0.w + h2 * q1.y + h3 * q1.w;
#pragma unroll
  for (int off = 1; off <= 32; off <<= 1) {
    s += __shfl_xor(s, off);
    d += __shfl_xor(d, off);
  }
  if (lane == 0) {
    a_s[n] = s;
    if (n < N2) a_d[n] = d;
  }
}

// ---------------- CSR build: both layers in one pass ----------------
__global__ void hist12_kernel(const int* __restrict__ ed1,
                              const int* __restrict__ ed2,
                              int* __restrict__ deg1, int* __restrict__ deg2,
                              int* __restrict__ rank1,
                              int* __restrict__ rank2) {
  int e = blockIdx.x * blockDim.x + threadIdx.x;
  if (e < E1) {
    rank1[e] = atomicAdd(&deg1[ed1[e]], 1);
  } else {
    int e2 = e - E1;
    if (e2 < E2) rank2[e2] = atomicAdd(&deg2[ed2[e2]], 1);
  }
}

// scanA: per-1024-tile sums for both layers (blocks [0,NB1) L1, [NB1,NB1+NB2) L2)
__global__ __launch_bounds__(256) void scanA12_kernel(
    const int* __restrict__ deg1, const int* __restrict__ deg2,
    int* __restrict__ part) {
  __shared__ int red[256];
  int b = blockIdx.x;
  const int* deg;
  int n, base;
  if (b < NB1) { deg = deg1; n = N1; base = b * 1024; }
  else { deg = deg2; n = N2; base = (b - NB1) * 1024; }
  int s = 0;
  for (int i = threadIdx.x; i < 1024; i += 256) {
    int idx = base + i;
    if (idx < n) s += deg[idx];
  }
  red[threadIdx.x] = s;
  __syncthreads();
  for (int off = 128; off >= 1; off >>= 1) {
    if (threadIdx.x < off) red[threadIdx.x] += red[threadIdx.x + off];
    __syncthreads();
  }
  if (threadIdx.x == 0) part[b] = red[0];
}

// scanC: local scan + inline block-prefix from raw partials
__global__ __launch_bounds__(256) void scanC12_kernel(
    const int* __restrict__ deg1, const int* __restrict__ deg2,
    const int* __restrict__ part, int* __restrict__ offs1,
    int* __restrict__ offs2) {
  __shared__ int tsum[256];
  int b = blockIdx.x;
  const int* deg;
  int n, pbase, bl;
  int* offs;
  if (b < NB1) { deg = deg1; n = N1; offs = offs1; pbase = 0; bl = b; }
  else { deg = deg2; n = N2; offs = offs2; pbase = NB1; bl = b - NB1; }
  int boff = 0;
  for (int i = 0; i < bl; i++) boff += part[pbase + i];
  int base = bl * 1024;
  int v[4];
  int s = 0;
#pragma unroll
  for (int k = 0; k < 4; k++) {
    int idx = base + threadIdx.x * 4 + k;
    v[k] = (idx < n) ? deg[idx] : 0;
    s += v[k];
  }
  tsum[threadIdx.x] = s;
  __syncthreads();
  for (int off = 1; off < 256; off <<= 1) {
    int t = (threadIdx.x >= off) ? tsum[threadIdx.x - off] : 0;
    __syncthreads();
    tsum[threadIdx.x] += t;
    __syncthreads();
  }
  int run = boff + ((threadIdx.x > 0) ? tsum[threadIdx.x - 1] : 0);
#pragma unroll
  for (int k = 0; k < 4; k++) {
    int idx = base + threadIdx.x * 4 + k;
    if (idx < n) {
      offs[idx] = run;
      run += v[k];
    }
  }
  if (bl == 0 && threadIdx.x == 0) offs[n] = (b < NB1) ? E1 : E2;
}

// scatter layer1 (no atomics: pos = offs[d] + rank[e])
__global__ void scatter1_kernel(const int* __restrict__ src,
                                const int* __restrict__ dst, int E,
                                const int* __restrict__ offs,
                                const int* __restrict__ rank,
                                const float* __restrict__ a_s,
                                const float* __restrict__ a_d,
                                int* __restrict__ csr_src,
                                float* __restrict__ csr_t) {
  int e = blockIdx.x * blockDim.x + threadIdx.x;
  if (e >= E) return;
  int s = src[e], d = dst[e];
  int p = offs[d] + rank[e];
  csr_src[p] = s;
  float4 as = *(const float4*)&a_s[s * 4];
  float4 ad = *(const float4*)&a_d[d * 4];
  float4 t;
  t.x = lrelu(as.x + ad.x);
  t.y = lrelu(as.y + ad.y);
  t.z = lrelu(as.z + ad.z);
  t.w = lrelu(as.w + ad.w);
  *(float4*)&csr_t[(long)p * 4] = t;
}

__global__ void scatter2_kernel(const int* __restrict__ src,
                                const int* __restrict__ dst, int E,
                                const int* __restrict__ offs,
                                const int* __restrict__ rank,
                                const float* __restrict__ a_s,
                                const float* __restrict__ a_d,
                                int* __restrict__ csr_src,
                                float* __restrict__ csr_t) {
  int e = blockIdx.x * blockDim.x + threadIdx.x;
  if (e >= E) return;
  int s = src[e], d = dst[e];
  int p = offs[d] + rank[e];
  csr_src[p] = s;
  csr_t[p] = lrelu(a_s[s] + a_d[d]);
}

// gather1 + fused softmax: wave per node, half-wave per edge (2 edges/step)
// lane: half = lane>>5, l32 = lane&31 covers channels [l32*4, l32*4+4)
__global__ __launch_bounds__(256) void gather1_kernel(
    const short* __restrict__ x, const int* __restrict__ csr_src,
    const float* __restrict__ csr_t, const int* __restrict__ offs,
    short* __restrict__ z1) {
  int wid = threadIdx.x >> 6, lane = threadIdx.x & 63;
  long d = (long)blockIdx.x * 4 + wid;
  if (d >= N1) return;
  int lo = offs[d], deg = offs[d + 1] - lo;
  // softmax stats over edges (lane-strided)
  float4 mx = make_float4(-INFINITY, -INFINITY, -INFINITY, -INFINITY);
  for (int j = lane; j < deg; j += 64) {
    float4 t = *(const float4*)&csr_t[(long)(lo + j) * 4];
    mx.x = fmaxf(mx.x, t.x);
    mx.y = fmaxf(mx.y, t.y);
    mx.z = fmaxf(mx.z, t.z);
    mx.w = fmaxf(mx.w, t.w);
  }
#pragma unroll
  for (int off = 1; off <= 32; off <<= 1) {
    mx.x = fmaxf(mx.x, __shfl_xor(mx.x, off));
    mx.y = fmaxf(mx.y, __shfl_xor(mx.y, off));
    mx.z = fmaxf(mx.z, __shfl_xor(mx.z, off));
    mx.w = fmaxf(mx.w, __shfl_xor(mx.w, off));
  }
  float4 den = make_float4(0.f, 0.f, 0.f, 0.f);
  for (int j = lane; j < deg; j += 64) {
    float4 t = *(const float4*)&csr_t[(long)(lo + j) * 4];
    den.x += __expf(t.x - mx.x);
    den.y += __expf(t.y - mx.y);
    den.z += __expf(t.z - mx.z);
    den.w += __expf(t.w - mx.w);
  }
#pragma unroll
  for (int off = 1; off <= 32; off <<= 1) {
    den.x += __shfl_xor(den.x, off);
    den.y += __shfl_xor(den.y, off);
    den.z += __shfl_xor(den.z, off);
    den.w += __shfl_xor(den.w, off);
  }
  float4 inv;
  inv.x = 1.f / (den.x + 1e-16f);
  inv.y = 1.f / (den.y + 1e-16f);
  inv.z = 1.f / (den.z + 1e-16f);
  inv.w = 1.f / (den.w + 1e-16f);
  // accumulate
  int half = lane >> 5, l32 = lane & 31;
  float acc[4][4] = {};
  for (int c0 = 0; c0 < deg; c0 += 64) {
    int rem = min(64, deg - c0);
    int p = lo + c0 + ((lane < rem) ? lane : 0);
    int mysrc = csr_src[p];
    float4 myw = make_float4(0.f, 0.f, 0.f, 0.f);
    if (lane < rem) {
      float4 t = *(const float4*)&csr_t[(long)p * 4];
      myw.x = __expf(t.x - mx.x) * inv.x;
      myw.y = __expf(t.y - mx.y) * inv.y;
      myw.z = __expf(t.z - mx.z) * inv.z;
      myw.w = __expf(t.w - mx.w) * inv.w;
    }
#pragma unroll 2
    for (int j = 0; j < rem; j += 2) {
      int sj = j + half;  // per-lane shuffle index (bpermute); OOB lanes carry w=0
      int s = __shfl(mysrc, sj);
      float w0 = __shfl(myw.x, sj);
      float w1 = __shfl(myw.y, sj);
      float w2 = __shfl(myw.z, sj);
      float w3 = __shfl(myw.w, sj);
      short4 xv = *(const short4*)&x[(long)s * 128 + l32 * 4];
      float f0 = bf2f(xv.x), f1 = bf2f(xv.y), f2 = bf2f(xv.z), f3 = bf2f(xv.w);
      acc[0][0] += w0 * f0; acc[0][1] += w0 * f1; acc[0][2] += w0 * f2; acc[0][3] += w0 * f3;
      acc[1][0] += w1 * f0; acc[1][1] += w1 * f1; acc[1][2] += w1 * f2; acc[1][3] += w1 * f3;
      acc[2][0] += w2 * f0; acc[2][1] += w2 * f1; acc[2][2] += w2 * f2; acc[2][3] += w2 * f3;
      acc[3][0] += w3 * f0; acc[3][1] += w3 * f1; acc[3][2] += w3 * f2; acc[3][3] += w3 * f3;
    }
  }
  // cross-half reduction
#pragma unroll
  for (int h = 0; h < 4; h++)
#pragma unroll
    for (int k = 0; k < 4; k++) acc[h][k] += __shfl_xor(acc[h][k], 32);
  if (half == 0) {
#pragma unroll
    for (int h = 0; h < 4; h++) {
      short4 o;
      o.x = f2bf(acc[h][0]);
      o.y = f2bf(acc[h][1]);
      o.z = f2bf(acc[h][2]);
      o.w = f2bf(acc[h][3]);
      *(short4*)&z1[d * 512 + h * 128 + l32 * 4] = o;
    }
  }
}

// gather2 + fused softmax: wave per node, half-wave per edge
// l32 covers channels [l32*8, l32*8+8)
__global__ __launch_bounds__(256) void gather2_kernel(
    const short* __restrict__ hid1, const int* __restrict__ csr_src,
    const float* __restrict__ csr_t, const int* __restrict__ offs,
    short* __restrict__ z2) {
  int wid = threadIdx.x >> 6, lane = threadIdx.x & 63;
  long d = (long)blockIdx.x * 4 + wid;
  if (d >= N2) return;
  int lo = offs[d], deg = offs[d + 1] - lo;
  float mx = -INFINITY;
  for (int j = lane; j < deg; j += 64) mx = fmaxf(mx, csr_t[lo + j]);
#pragma unroll
  for (int off = 1; off <= 32; off <<= 1) mx = fmaxf(mx, __shfl_xor(mx, off));
  float den = 0.f;
  for (int j = lane; j < deg; j += 64) den += __expf(csr_t[lo + j] - mx);
#pragma unroll
  for (int off = 1; off <= 32; off <<= 1) den += __shfl_xor(den, off);
  float inv = 1.f / (den + 1e-16f);
  int half = lane >> 5, l32 = lane & 31;
  int ch0 = l32 * 8;
  float acc[8] = {};
  for (int c0 = 0; c0 < deg; c0 += 64) {
    int rem = min(64, deg - c0);
    int p = lo + c0 + ((lane < rem) ? lane : 0);
    int mysrc = csr_src[p];
    float myw = (lane < rem) ? __expf(csr_t[p] - mx) * inv : 0.f;
#pragma unroll 2
    for (int j = 0; j < rem; j += 2) {
      int sj = j + half;
      int s = __shfl(mysrc, sj);
      float wv = __shfl(myw, sj);
      bf16x8 v = *(const bf16x8*)&hid1[(long)s * 256 + ch0];
#pragma unroll
      for (int k = 0; k < 8; k++) acc[k] += wv * bf2f(v[k]);
    }
  }
#pragma unroll
  for (int k = 0; k < 8; k++) acc[k] += __shfl_xor(acc[k], 32);
  if (half == 0) {
    bf16x8 o;
#pragma unroll
    for (int k = 0; k < 8; k++) o[k] = f2bf(acc[k]);
    *(bf16x8*)&z2[d * 256 + ch0] = o;
  }
}

extern "C" void kernel_launch(void* const* d_in, const int* in_sizes, int n_in,
                              void* d_out, int out_size, void* d_ws,
                              size_t ws_size, hipStream_t stream) {
  const float* x = (const float*)d_in[0];
  const int* es1 = (const int*)d_in[1];
  const int* ed1 = (const int*)d_in[2];
  const int* es2 = (const int*)d_in[3];
  const int* ed2 = (const int*)d_in[4];
  const float* W1 = (const float*)d_in[5];
  const float* att_s1 = (const float*)d_in[6];
  const float* att_d1 = (const float*)d_in[7];
  const float* b1 = (const float*)d_in[8];
  const float* W2 = (const float*)d_in[9];
  const float* att_s2 = (const float*)d_in[10];
  const float* att_d2 = (const float*)d_in[11];
  const float* b2 = (const float*)d_in[12];
  const float* c1w = (const float*)d_in[13];
  const float* c1b = (const float*)d_in[14];
  const float* c2w = (const float*)d_in[15];
  const float* c2b = (const float*)d_in[16];
  float* out = (float*)d_out;

  char* ws = (char*)d_ws;
  size_t off = 0;
  auto alloc = [&](size_t bytes) {
    void* p = ws + off;
    off += (bytes + 255) & ~(size_t)255;
    return p;
  };
  short* x_bf = (short*)alloc((size_t)N0 * 128 * 2);
  short* z1 = (short*)alloc((size_t)N1 * 512 * 2);
  short* hid1 = (short*)alloc((size_t)N1 * 256 * 2);
  short* z2 = (short*)alloc((size_t)N2 * 256 * 2);
  float* p1 = (float*)alloc(128 * 8 * 4);
  short* M1t = (short*)alloc(256 * 512 * 2);
  float* bias1p = (float*)alloc(256 * 4);
  float* p2 = (float*)alloc(256 * 2 * 4);
  short* M2t = (short*)alloc(128 * 256 * 2);
  float* bias2p = (float*)alloc(128 * 4);
  float* as1 = (float*)alloc((size_t)N0 * 4 * 4);
  float* ad1v = (float*)alloc((size_t)N1 * 4 * 4);
  float* as2 = (float*)alloc((size_t)N1 * 4);
  float* ad2v = (float*)alloc((size_t)N2 * 4);
  int* deg1 = (int*)alloc((size_t)N1 * 4);   // N1*4 = 160000, 256-aligned
  int* deg2 = (int*)alloc((size_t)N2 * 4);   // adjacent to deg1
  int* offs1 = (int*)alloc((size_t)(N1 + 1) * 4);
  int* rank1 = (int*)alloc((size_t)E1 * 4);
  int* offs2 = (int*)alloc((size_t)(N2 + 1) * 4);
  int* rank2 = (int*)alloc((size_t)E2 * 4);
  int* part12 = (int*)alloc(64 * 4);
  int* csr_src1 = (int*)alloc((size_t)E1 * 4);
  float* csr_t1 = (float*)alloc((size_t)E1 * 4 * 4);
  int* csr_src2 = (int*)alloc((size_t)E2 * 4);
  float* csr_t2 = (float*)alloc((size_t)E2 * 4);

  // deg1 and deg2 are adjacent -> single memset
  hipMemsetAsync(deg1, 0, (size_t)N1 * 4 + (size_t)N2 * 4, stream);

  prep_all_kernel<<<648, 256, 0, stream>>>(W1, att_s1, att_d1, b1, c1w, c1b,
                                           W2, att_s2, att_d2, b2, c2w, c2b,
                                           M1t, p1, bias1p, M2t, p2, bias2p);
  cast_attn1_kernel<<<(N0 + 3) / 4, 256, 0, stream>>>(x, p1, x_bf, as1, ad1v);
  hist12_kernel<<<(E1 + E2 + 255) / 256, 256, 0, stream>>>(ed1, ed2, deg1,
                                                           deg2, rank1, rank2);
  scanA12_kernel<<<NB1 + NB2, 256, 0, stream>>>(deg1, deg2, part12);
  scanC12_kernel<<<NB1 + NB2, 256, 0, stream>>>(deg1, deg2, part12, offs1,
                                                offs2);
  scatter1_kernel<<<(E1 + 255) / 256, 256, 0, stream>>>(
      es1, ed1, E1, offs1, rank1, as1, ad1v, csr_src1, csr_t1);
  gather1_kernel<<<(N1 + 3) / 4, 256, 0, stream>>>(x_bf, csr_src1, csr_t1,
                                                   offs1, z1);
  mm_bf16_kernel<true, true><<<dim3(4, (N1 + 127) / 128), 256, 0, stream>>>(
      z1, M1t, bias1p, hid1, N1, 256, 512);

  attn2_kernel<<<(N1 + 3) / 4, 256, 0, stream>>>(hid1, p2, as2, ad2v);
  scatter2_kernel<<<(E2 + 255) / 256, 256, 0, stream>>>(
      es2, ed2, E2, offs2, rank2, as2, ad2v, csr_src2, csr_t2);
  gather2_kernel<<<(N2 + 3) / 4, 256, 0, stream>>>(hid1, csr_src2, csr_t2,
                                                   offs2, z2);
  mm_bf16_kernel<true, false><<<dim3(2, (N2 + 127) / 128), 256, 0, stream>>>(
      z2, M2t, bias2p, out, N2, 128, 256);
}